// Round 8
// baseline (197.401 us; speedup 1.0000x reference)
//
#include <hip/hip_runtime.h>
#include <stdint.h>

#define B_SZ 8192
#define N_SZ 256
#define H_SZ 2048
#define LOG2PI_F 1.8378770664093453f
#define BETA_F 0.99f

typedef unsigned short ushort_t;
typedef __attribute__((ext_vector_type(8))) __bf16 bf16x8;
typedef __attribute__((ext_vector_type(4))) float f32x4;
typedef __attribute__((ext_vector_type(8))) ushort_t u16x8;

__device__ __forceinline__ ushort_t f2bf(float f) {
    unsigned int u = __float_as_uint(f);
    unsigned int r = (u + 0x7FFFu + ((u >> 16) & 1u)) >> 16;  // RNE
    return (ushort_t)r;
}

__device__ __forceinline__ float fast_tanh(float v) {
    float ex = __expf(2.0f * v);
    return 1.0f - __fdividef(2.0f, ex + 1.0f);
}

__device__ __forceinline__ void async_ld16(const void* g, const char* lds_uniform) {
    __builtin_amdgcn_global_load_lds(
        (const __attribute__((address_space(1))) void*)g,
        (__attribute__((address_space(3))) void*)lds_uniform,
        16, 0, 0);
}

// GEMM1 (tanh -> h) fused with Vx. 128x128 LDS tiles, BK=32, K=256.
// grid (18, 64): x<16 -> W1 path; else Wv path. 4 blocks/CU (VGPR ~96 <= 128).
__global__ __launch_bounds__(256, 4)
void gemm1_vx_kernel(const ushort_t* __restrict__ xb, const ushort_t* __restrict__ W1p,
                     const ushort_t* __restrict__ Wvp, const float* __restrict__ b1,
                     ushort_t* __restrict__ h, float* __restrict__ vx)
{
    __shared__ __align__(16) char smem[16384];
    char* sA = smem;          // [4][128][8] bf16 = 8 KB
    char* sB = smem + 8192;   // [4][128][8] bf16 = 8 KB
    const int tid = threadIdx.x;
    const int lane = tid & 63;
    const int w = tid >> 6;
    const int q = lane >> 4;
    const int rlo = lane & 15;
    const int wr = w >> 1, wc = w & 1;
    const int row0 = blockIdx.y * 128;

    const bool w1path = blockIdx.x < 16;
    const int n0 = (w1path ? blockIdx.x : blockIdx.x - 16) * 128;
    const ushort_t* Bp = w1path ? W1p : Wvp;
    const int N = w1path ? H_SZ : N_SZ;

    f32x4 acc[4][4];
#pragma unroll
    for (int i = 0; i < 4; ++i)
#pragma unroll
        for (int j = 0; j < 4; ++j)
            acc[i][j] = f32x4{0.f, 0.f, 0.f, 0.f};

    for (int k0 = 0; k0 < N_SZ; k0 += 32) {
        __syncthreads();
#pragma unroll
        for (int r = 0; r < 2; ++r) {
            int c = r * 256 + tid;
            int m = c & 127, kc = c >> 7;
            async_ld16(xb + (size_t)(row0 + m) * N_SZ + k0 + kc * 8, sA + (c << 4));
        }
        int ko0 = k0 >> 3;
#pragma unroll
        for (int r = 0; r < 2; ++r) {
            int c = r * 256 + tid;
            int kq = c >> 7, n = c & 127;
            async_ld16(Bp + ((size_t)(ko0 + kq) * N + n0 + n) * 8, sB + (c << 4));
        }
        __syncthreads();

        bf16x8 af[4], bfr[4];
#pragma unroll
        for (int i = 0; i < 4; ++i)
            af[i] = *(const bf16x8*)(sA + (((q << 7) + wr * 64 + i * 16 + rlo) << 4));
#pragma unroll
        for (int j = 0; j < 4; ++j)
            bfr[j] = *(const bf16x8*)(sB + (((q << 7) + wc * 64 + j * 16 + rlo) << 4));
#pragma unroll
        for (int i = 0; i < 4; ++i)
#pragma unroll
            for (int j = 0; j < 4; ++j)
                acc[i][j] = __builtin_amdgcn_mfma_f32_16x16x32_bf16(af[i], bfr[j], acc[i][j], 0, 0, 0);
    }

    if (w1path) {
#pragma unroll
        for (int j = 0; j < 4; ++j) {
            int col = n0 + wc * 64 + j * 16 + rlo;
            float bv = b1[col];
#pragma unroll
            for (int i = 0; i < 4; ++i) {
                int rowb = row0 + wr * 64 + i * 16 + q * 4;
#pragma unroll
                for (int rr = 0; rr < 4; ++rr)
                    h[(size_t)(rowb + rr) * H_SZ + col] = f2bf(fast_tanh(acc[i][j][rr] + bv));
            }
        }
    } else {
#pragma unroll
        for (int i = 0; i < 4; ++i) {
#pragma unroll
            for (int rr = 0; rr < 4; ++rr) {
                float s = 0.f;
#pragma unroll
                for (int j = 0; j < 4; ++j) { float v = acc[i][j][rr]; s += v * v; }
#pragma unroll
                for (int m = 1; m < 16; m <<= 1) s += __shfl_xor(s, m, 64);
                if (rlo == 0)
                    atomicAdd(&vx[row0 + wr * 64 + i * 16 + q * 4 + rr], s);
            }
        }
    }
}

// GEMM2: f = h@W2 + b2, mub = bf16(f[:, :256]). 64x64 tiles, BK=64,
// K=2048, grid (8, 128) = 1024 blocks = 4/CU. Each wave: 32x32 out.
__global__ __launch_bounds__(256, 4)
void gemm2_kernel(const ushort_t* __restrict__ h, const ushort_t* __restrict__ W2p,
                  const float* __restrict__ b2, float* __restrict__ f,
                  ushort_t* __restrict__ mub)
{
    __shared__ __align__(16) char smem[16384];
    char* sA = smem;          // [8][64][8] bf16 = 8 KB
    char* sB = smem + 8192;   // [8][64][8] bf16 = 8 KB
    const int tid = threadIdx.x;
    const int lane = tid & 63;
    const int w = tid >> 6;
    const int q = lane >> 4;
    const int rlo = lane & 15;
    const int wr = w >> 1, wc = w & 1;
    const int row0 = blockIdx.y * 64;
    const int n0 = blockIdx.x * 64;

    f32x4 acc[2][2];
#pragma unroll
    for (int i = 0; i < 2; ++i)
#pragma unroll
        for (int j = 0; j < 2; ++j)
            acc[i][j] = f32x4{0.f, 0.f, 0.f, 0.f};

    for (int k0 = 0; k0 < H_SZ; k0 += 64) {
        __syncthreads();
#pragma unroll
        for (int r = 0; r < 2; ++r) {   // A: 512 chunks, layout [kq][m][8]
            int c = r * 256 + tid;
            int kq = c >> 6, m = c & 63;
            async_ld16(h + (size_t)(row0 + m) * H_SZ + k0 + kq * 8, sA + (c << 4));
        }
        int ko0 = k0 >> 3;
#pragma unroll
        for (int r = 0; r < 2; ++r) {   // B: 512 chunks, layout [kq][n][8]
            int c = r * 256 + tid;
            int kq = c >> 6, n = c & 63;
            async_ld16(W2p + ((size_t)(ko0 + kq) * 512 + n0 + n) * 8,
                       sB + 8192 + (c << 4) - 8192 + (c << 4) * 0 + 0);
        }
        __syncthreads();
        // NOTE: the sB pointer arithmetic above must be plain; fixed below.
    }
    // (unreachable placeholder removed in real loop below)
}

// -- real gemm2 (the above stub is unused); kept single definition clean ----

__global__ __launch_bounds__(256, 4)
void gemm2_kernel_real(const ushort_t* __restrict__ h, const ushort_t* __restrict__ W2p,
                       const float* __restrict__ b2, float* __restrict__ f,
                       ushort_t* __restrict__ mub)
{
    __shared__ __align__(16) char smem[16384];
    char* sA = smem;          // [8][64][8] bf16 = 8 KB
    char* sB = smem + 8192;   // [8][64][8] bf16 = 8 KB
    const int tid = threadIdx.x;
    const int lane = tid & 63;
    const int w = tid >> 6;
    const int q = lane >> 4;
    const int rlo = lane & 15;
    const int wr = w >> 1, wc = w & 1;
    const int row0 = blockIdx.y * 64;
    const int n0 = blockIdx.x * 64;

    f32x4 acc[2][2];
#pragma unroll
    for (int i = 0; i < 2; ++i)
#pragma unroll
        for (int j = 0; j < 2; ++j)
            acc[i][j] = f32x4{0.f, 0.f, 0.f, 0.f};

    for (int k0 = 0; k0 < H_SZ; k0 += 64) {
        __syncthreads();
#pragma unroll
        for (int r = 0; r < 2; ++r) {   // A: 512 chunks, layout [kq][m][8]
            int c = r * 256 + tid;
            int kq = c >> 6, m = c & 63;
            async_ld16(h + (size_t)(row0 + m) * H_SZ + k0 + kq * 8, sA + (c << 4));
        }
        int ko0 = k0 >> 3;
#pragma unroll
        for (int r = 0; r < 2; ++r) {   // B: 512 chunks, layout [kq][n][8]
            int c = r * 256 + tid;
            int kq = c >> 6, n = c & 63;
            async_ld16(W2p + ((size_t)(ko0 + kq) * 512 + n0 + n) * 8, sB + (c << 4));
        }
        __syncthreads();

#pragma unroll
        for (int ks = 0; ks < 2; ++ks) {
            int kq = ks * 4 + q;
            bf16x8 af[2], bfr[2];
#pragma unroll
            for (int i = 0; i < 2; ++i)
                af[i] = *(const bf16x8*)(sA + (((kq << 6) + wr * 32 + i * 16 + rlo) << 4));
#pragma unroll
            for (int j = 0; j < 2; ++j)
                bfr[j] = *(const bf16x8*)(sB + (((kq << 6) + wc * 32 + j * 16 + rlo) << 4));
#pragma unroll
            for (int i = 0; i < 2; ++i)
#pragma unroll
                for (int j = 0; j < 2; ++j)
                    acc[i][j] = __builtin_amdgcn_mfma_f32_16x16x32_bf16(af[i], bfr[j], acc[i][j], 0, 0, 0);
        }
    }

#pragma unroll
    for (int j = 0; j < 2; ++j) {
        int col = n0 + wc * 32 + j * 16 + rlo;
        float bv = b2[col];
#pragma unroll
        for (int i = 0; i < 2; ++i) {
            int rowb = row0 + wr * 32 + i * 16 + q * 4;
#pragma unroll
            for (int rr = 0; rr < 4; ++rr) {
                float v = acc[i][j][rr] + bv;
                f[(size_t)(rowb + rr) * 512 + col] = v;
                if (col < N_SZ)
                    mub[(size_t)(rowb + rr) * N_SZ + col] = f2bf(v);
            }
        }
    }
}

// Vmu = rowsumsq(mu@Wv). K=256 flat, split 4 ways in-block. grid (128, 4).
template<int KSTEPS>
__device__ __forceinline__ void gemm_ksplit(
    const ushort_t* __restrict__ A, const ushort_t* __restrict__ Bp,
    int K, int N, int row0, int col0, int w, int q, int rlo,
    f32x4 acc[4][4])
{
    const int kbase = w * (K / 4);
    const ushort_t* a0 = A + (size_t)(row0 + rlo) * K + kbase + q * 8;
    const ushort_t* b0 = Bp + ((size_t)(kbase / 8 + q) * N + col0 + rlo) * 8;
#pragma unroll
    for (int s = 0; s < KSTEPS; ++s) {
        bf16x8 af[4], bfr[4];
#pragma unroll
        for (int i = 0; i < 4; ++i)
            af[i] = *(const bf16x8*)(a0 + i * 16 * K + s * 32);
#pragma unroll
        for (int j = 0; j < 4; ++j)
            bfr[j] = *(const bf16x8*)(b0 + s * 4 * N * 8 + j * 128);
#pragma unroll
        for (int i = 0; i < 4; ++i)
#pragma unroll
            for (int j = 0; j < 4; ++j)
                acc[i][j] = __builtin_amdgcn_mfma_f32_16x16x32_bf16(af[i], bfr[j], acc[i][j], 0, 0, 0);
    }
}

__global__ __launch_bounds__(256, 4)
void gemmv_kernel(const ushort_t* __restrict__ mub, const ushort_t* __restrict__ Wvp,
                  float* __restrict__ vmu)
{
    __shared__ float sl[2][3][16][64];
    const int tid = threadIdx.x;
    const int lane = tid & 63;
    const int w = tid >> 6;
    const int q = lane >> 4;
    const int rlo = lane & 15;
    const int row0 = blockIdx.x * 64;
    const int col0 = blockIdx.y * 64;

    f32x4 acc[4][4];
#pragma unroll
    for (int i = 0; i < 4; ++i)
#pragma unroll
        for (int j = 0; j < 4; ++j)
            acc[i][j] = f32x4{0.f, 0.f, 0.f, 0.f};

    gemm_ksplit<2>(mub, Wvp, N_SZ, N_SZ, row0, col0, w, q, rlo, acc);

#pragma unroll
    for (int p = 0; p < 2; ++p) {
        int c0 = 2 * p, c1 = 2 * p + 1;
        if (p) __syncthreads();
        if (w != c0) {
            int idx = w - (w > c0 ? 1 : 0);
#pragma unroll
            for (int j = 0; j < 4; ++j)
#pragma unroll
                for (int rr = 0; rr < 4; ++rr)
                    sl[0][idx][j * 4 + rr][lane] = acc[c0][j][rr];
        }
        if (w != c1) {
            int idx = w - (w > c1 ? 1 : 0);
#pragma unroll
            for (int j = 0; j < 4; ++j)
#pragma unroll
                for (int rr = 0; rr < 4; ++rr)
                    sl[1][idx][j * 4 + rr][lane] = acc[c1][j][rr];
        }
        __syncthreads();
        if (w == c0 || w == c1) {
            int slot = (w == c0) ? 0 : 1;
#pragma unroll
            for (int rr = 0; rr < 4; ++rr) {
                float s = 0.f;
#pragma unroll
                for (int j = 0; j < 4; ++j) {
                    float v = acc[w][j][rr]
                            + sl[slot][0][j * 4 + rr][lane]
                            + sl[slot][1][j * 4 + rr][lane]
                            + sl[slot][2][j * 4 + rr][lane];
                    s += v * v;
                }
#pragma unroll
                for (int m = 1; m < 16; m <<= 1) s += __shfl_xor(s, m, 64);
                if (rlo == 0)
                    atomicAdd(&vmu[row0 + w * 16 + q * 4 + rr], s);
            }
        }
    }
}

// Conversion, fully coalesced: one thread per 8-element k-chunk.
// x: 262144 chunks; W1: [32 ko][2048 n]; W2: [256 ko][512 n]; Wv: [32 ko][256 n].
__global__ __launch_bounds__(256)
void convert_kernel(const float* __restrict__ x, const float* __restrict__ W1,
                    const float* __restrict__ W2, const float* __restrict__ Wv,
                    ushort_t* __restrict__ xb, ushort_t* __restrict__ W1p,
                    ushort_t* __restrict__ W2p, ushort_t* __restrict__ Wvp)
{
    const int XC = 262144, W1C = 65536, W2C = 131072;
    int c = blockIdx.x * 256 + threadIdx.x;
    if (c < XC) {
        f32x4 a = *(const f32x4*)(x + (size_t)c * 8);
        f32x4 b = *(const f32x4*)(x + (size_t)c * 8 + 4);
        u16x8 o;
#pragma unroll
        for (int i = 0; i < 4; ++i) { o[i] = f2bf(a[i]); o[4 + i] = f2bf(b[i]); }
        *(u16x8*)(xb + (size_t)c * 8) = o;
    } else if (c < XC + W1C) {
        int d = c - XC;
        int ko = d >> 11, n = d & 2047;
        u16x8 o;
#pragma unroll
        for (int ki = 0; ki < 8; ++ki)
            o[ki] = f2bf(W1[(size_t)(ko * 8 + ki) * H_SZ + n]);
        *(u16x8*)(W1p + (size_t)d * 8) = o;
    } else if (c < XC + W1C + W2C) {
        int d = c - XC - W1C;
        int ko = d >> 9, n = d & 511;
        u16x8 o;
#pragma unroll
        for (int ki = 0; ki < 8; ++ki)
            o[ki] = f2bf(W2[(size_t)(ko * 8 + ki) * 512 + n]);
        *(u16x8*)(W2p + (size_t)d * 8) = o;
    } else {
        int d = c - XC - W1C - W2C;
        int ko = d >> 8, n = d & 255;
        u16x8 o;
#pragma unroll
        for (int ki = 0; ki < 8; ++ki)
            o[ki] = f2bf(Wv[(size_t)(ko * 8 + ki) * N_SZ + n]);
        *(u16x8*)(Wvp + (size_t)d * 8) = o;
    }
}

// per-row: scale ; fx ; logp row-sum -> partials[b]
__global__ __launch_bounds__(256)
void epilogue_kernel(const float* __restrict__ f, const float* __restrict__ y,
                     const float* __restrict__ eps, const float* __restrict__ vx,
                     const float* __restrict__ vmu, float* __restrict__ out,
                     float* __restrict__ partials)
{
    int b = blockIdx.x;
    int n = threadIdx.x;
    size_t bi = (size_t)b;
    float mu = f[bi * 512 + n];
    float lv = f[bi * 512 + 256 + n];
    float var = expf(lv);
    float Vx = vx[b] + 1e-3f;
    float Vmu = vmu[b] + 1e-3f;
    float scale = fminf(BETA_F * Vx, Vmu) / Vmu;
    float mus = mu * scale;
    float e = eps[bi * 256 + n];
    float yy = y[bi * 256 + n];
    out[bi * 256 + n] = mus + sqrtf(var) * e;
    float d = yy - mus;
    float t = lv + d * d / var;
#pragma unroll
    for (int m = 32; m >= 1; m >>= 1) t += __shfl_down(t, m, 64);
    __shared__ float red[4];
    int lane = n & 63, wv = n >> 6;
    if (lane == 0) red[wv] = t;
    __syncthreads();
    if (n == 0)
        partials[b] = red[0] + red[1] + red[2] + red[3];
}

// single block: sum B_SZ partials, write scalar logp_y
__global__ __launch_bounds__(256)
void reduce_kernel(const float* __restrict__ partials, float* __restrict__ out)
{
    int tid = threadIdx.x;
    float s = 0.f;
#pragma unroll
    for (int i = 0; i < B_SZ / (256 * 4); ++i) {
        f32x4 v = *(const f32x4*)(partials + i * 1024 + tid * 4);
        s += v[0] + v[1] + v[2] + v[3];
    }
#pragma unroll
    for (int m = 32; m >= 1; m >>= 1) s += __shfl_down(s, m, 64);
    __shared__ float red[4];
    int lane = tid & 63, wv = tid >> 6;
    if (lane == 0) red[wv] = s;
    __syncthreads();
    if (tid == 0) {
        float tot = red[0] + red[1] + red[2] + red[3];
        out[(size_t)B_SZ * N_SZ] =
            0.5f * (tot + (float)N_SZ * LOG2PI_F * (float)B_SZ);
    }
}

extern "C" void kernel_launch(void* const* d_in, const int* in_sizes, int n_in,
                              void* d_out, int out_size, void* d_ws, size_t ws_size,
                              hipStream_t stream)
{
    const float* x   = (const float*)d_in[0];
    const float* y   = (const float*)d_in[1];
    const float* eps = (const float*)d_in[2];
    const float* W1  = (const float*)d_in[3];
    const float* b1  = (const float*)d_in[4];
    const float* W2  = (const float*)d_in[5];
    const float* b2  = (const float*)d_in[6];
    const float* Wv  = (const float*)d_in[7];
    float* out = (float*)d_out;

    char* ws = (char*)d_ws;
    size_t off = 0;
    auto alloc = [&](size_t bytes) {
        char* p = ws + off;
        off += (bytes + 255) & ~(size_t)255;
        return p;
    };
    ushort_t* xb  = (ushort_t*)alloc((size_t)B_SZ * N_SZ * 2);
    ushort_t* W1p = (ushort_t*)alloc((size_t)N_SZ * H_SZ * 2);
    ushort_t* W2p = (ushort_t*)alloc((size_t)H_SZ * 512 * 2);
    ushort_t* Wvp = (ushort_t*)alloc((size_t)N_SZ * N_SZ * 2);
    ushort_t* h   = (ushort_t*)alloc((size_t)B_SZ * H_SZ * 2);
    float*    f   = (float*)alloc((size_t)B_SZ * 512 * 4);
    ushort_t* mub = (ushort_t*)alloc((size_t)B_SZ * N_SZ * 2);
    float*    vx  = (float*)alloc((size_t)B_SZ * 4);
    float*    vmu = (float*)alloc((size_t)B_SZ * 4);
    float*    partials = (float*)alloc((size_t)B_SZ * 4);

    hipMemsetAsync(vx, 0, (size_t)B_SZ * 4, stream);
    hipMemsetAsync(vmu, 0, (size_t)B_SZ * 4, stream);

    const int TOTALC = 262144 + 65536 + 131072 + 8192;  // 466944 chunks
    convert_kernel<<<TOTALC / 256, 256, 0, stream>>>(x, W1, W2, Wv, xb, W1p, W2p, Wvp);

    // h = tanh(x@W1 + b1)  (+ fused Vx), 128x128 LDS tiles, 4 blocks/CU
    gemm1_vx_kernel<<<dim3(18, B_SZ / 128), 256, 0, stream>>>(xb, W1p, Wvp, b1, h, vx);
    // f = h@W2 + b2 ; mub = bf16(mu), 64x64 tiles BK=64, 1024 blocks
    gemm2_kernel_real<<<dim3(8, B_SZ / 64), 256, 0, stream>>>(h, W2p, b2, f, mub);
    // Vmu = rowsumsq(mu@Wv)
    gemmv_kernel<<<dim3(B_SZ / 64, 4), 256, 0, stream>>>(mub, Wvp, vmu);

    epilogue_kernel<<<B_SZ, 256, 0, stream>>>(f, y, eps, vx, vmu, out, partials);
    reduce_kernel<<<1, 256, 0, stream>>>(partials, out);
}

// Round 9
// 175.074 us; speedup vs baseline: 1.1275x; 1.1275x over previous
//
#include <hip/hip_runtime.h>
#include <stdint.h>

#define B_SZ 8192
#define N_SZ 256
#define H_SZ 2048
#define LOG2PI_F 1.8378770664093453f
#define BETA_F 0.99f

typedef unsigned short ushort_t;
typedef __attribute__((ext_vector_type(8))) __bf16 bf16x8;
typedef __attribute__((ext_vector_type(4))) float f32x4;
typedef __attribute__((ext_vector_type(8))) ushort_t u16x8;

__device__ __forceinline__ ushort_t f2bf(float f) {
    unsigned int u = __float_as_uint(f);
    unsigned int r = (u + 0x7FFFu + ((u >> 16) & 1u)) >> 16;  // RNE
    return (ushort_t)r;
}

__device__ __forceinline__ float fast_tanh(float v) {
    float ex = __expf(2.0f * v);
    return 1.0f - __fdividef(2.0f, ex + 1.0f);
}

__device__ __forceinline__ void async_ld16(const void* g, const char* lds_uniform) {
    __builtin_amdgcn_global_load_lds(
        (const __attribute__((address_space(1))) void*)g,
        (__attribute__((address_space(3))) void*)lds_uniform,
        16, 0, 0);
}

// GEMM1 (tanh -> h) fused with Vx. 128x128 LDS tiles, BK=64, K=256 (4 iters).
// grid (18, 64): x<16 -> W1 path; else Wv path.
__global__ __launch_bounds__(256, 4)
void gemm1_vx_kernel(const ushort_t* __restrict__ xb, const ushort_t* __restrict__ W1p,
                     const ushort_t* __restrict__ Wvp, const float* __restrict__ b1,
                     ushort_t* __restrict__ h, float* __restrict__ vx)
{
    __shared__ __align__(16) char smem[32768];
    char* sA = smem;           // [8 kq][128 m][8] bf16 = 16 KB
    char* sB = smem + 16384;   // [8 kq][128 n][8] bf16 = 16 KB
    const int tid = threadIdx.x;
    const int lane = tid & 63;
    const int w = tid >> 6;
    const int q = lane >> 4;
    const int rlo = lane & 15;
    const int wr = w >> 1, wc = w & 1;
    const int row0 = blockIdx.y * 128;

    const bool w1path = blockIdx.x < 16;
    const int n0 = (w1path ? blockIdx.x : blockIdx.x - 16) * 128;
    const ushort_t* Bp = w1path ? W1p : Wvp;
    const int N = w1path ? H_SZ : N_SZ;

    f32x4 acc[4][4];
#pragma unroll
    for (int i = 0; i < 4; ++i)
#pragma unroll
        for (int j = 0; j < 4; ++j)
            acc[i][j] = f32x4{0.f, 0.f, 0.f, 0.f};

    for (int k0 = 0; k0 < N_SZ; k0 += 64) {
        __syncthreads();
#pragma unroll
        for (int r = 0; r < 4; ++r) {
            int c = r * 256 + tid;
            int kq = c >> 7, m = c & 127;
            async_ld16(xb + (size_t)(row0 + m) * N_SZ + k0 + kq * 8, sA + (c << 4));
        }
        int ko0 = k0 >> 3;
#pragma unroll
        for (int r = 0; r < 4; ++r) {
            int c = r * 256 + tid;
            int kq = c >> 7, n = c & 127;
            async_ld16(Bp + ((size_t)(ko0 + kq) * N + n0 + n) * 8, sB + (c << 4));
        }
        __syncthreads();

#pragma unroll
        for (int ks = 0; ks < 2; ++ks) {
            int kq = ks * 4 + q;
            bf16x8 af[4], bfr[4];
#pragma unroll
            for (int i = 0; i < 4; ++i)
                af[i] = *(const bf16x8*)(sA + (((kq << 7) + wr * 64 + i * 16 + rlo) << 4));
#pragma unroll
            for (int j = 0; j < 4; ++j)
                bfr[j] = *(const bf16x8*)(sB + (((kq << 7) + wc * 64 + j * 16 + rlo) << 4));
#pragma unroll
            for (int i = 0; i < 4; ++i)
#pragma unroll
                for (int j = 0; j < 4; ++j)
                    acc[i][j] = __builtin_amdgcn_mfma_f32_16x16x32_bf16(af[i], bfr[j], acc[i][j], 0, 0, 0);
        }
    }

    if (w1path) {
#pragma unroll
        for (int j = 0; j < 4; ++j) {
            int col = n0 + wc * 64 + j * 16 + rlo;
            float bv = b1[col];
#pragma unroll
            for (int i = 0; i < 4; ++i) {
                int rowb = row0 + wr * 64 + i * 16 + q * 4;
#pragma unroll
                for (int rr = 0; rr < 4; ++rr)
                    h[(size_t)(rowb + rr) * H_SZ + col] = f2bf(fast_tanh(acc[i][j][rr] + bv));
            }
        }
    } else {
#pragma unroll
        for (int i = 0; i < 4; ++i) {
#pragma unroll
            for (int rr = 0; rr < 4; ++rr) {
                float s = 0.f;
#pragma unroll
                for (int j = 0; j < 4; ++j) { float v = acc[i][j][rr]; s += v * v; }
#pragma unroll
                for (int m = 1; m < 16; m <<= 1) s += __shfl_xor(s, m, 64);
                if (rlo == 0)
                    atomicAdd(&vx[row0 + wr * 64 + i * 16 + q * 4 + rr], s);
            }
        }
    }
}

// GEMM2: f = h@W2 + b2, mub = bf16(f[:, :256]). 64x128 tiles, BK=64, K=2048.
// grid 512 (1D) with XCD swizzle: the 4 col-blocks of each 64-row stripe land
// on the same XCD so the h stripe is fetched into that XCD's L2 once.
__global__ __launch_bounds__(256, 4)
void gemm2_kernel(const ushort_t* __restrict__ h, const ushort_t* __restrict__ W2p,
                  const float* __restrict__ b2, float* __restrict__ f,
                  ushort_t* __restrict__ mub)
{
    __shared__ __align__(16) char smem[24576];
    char* sA = smem;          // [8 kq][64 m][8] bf16 = 8 KB
    char* sB = smem + 8192;   // [8 kq][128 n][8] bf16 = 16 KB
    const int tid = threadIdx.x;
    const int lane = tid & 63;
    const int w = tid >> 6;
    const int q = lane >> 4;
    const int rlo = lane & 15;
    const int wr = w >> 1, wc = w & 1;

    // swizzle: bid -> (stripe s, col c) with s%8 == bid%8 (XCD affinity)
    const int bid = blockIdx.x;
    const int r8 = bid & 7;
    const int u = bid >> 3;
    const int cb = u & 3;
    const int tb = u >> 2;
    const int row0 = (r8 + 8 * tb) * 64;
    const int n0 = cb * 128;

    f32x4 acc[2][4];
#pragma unroll
    for (int i = 0; i < 2; ++i)
#pragma unroll
        for (int j = 0; j < 4; ++j)
            acc[i][j] = f32x4{0.f, 0.f, 0.f, 0.f};

    for (int k0 = 0; k0 < H_SZ; k0 += 64) {
        __syncthreads();
#pragma unroll
        for (int r = 0; r < 2; ++r) {   // A: 512 chunks, layout [kq][m][8]
            int c = r * 256 + tid;
            int kq = c >> 6, m = c & 63;
            async_ld16(h + (size_t)(row0 + m) * H_SZ + k0 + kq * 8, sA + (c << 4));
        }
        int ko0 = k0 >> 3;
#pragma unroll
        for (int r = 0; r < 4; ++r) {   // B: 1024 chunks, layout [kq][n][8]
            int c = r * 256 + tid;
            int kq = c >> 7, n = c & 127;
            async_ld16(W2p + ((size_t)(ko0 + kq) * 512 + n0 + n) * 8, sB + (c << 4));
        }
        __syncthreads();

#pragma unroll
        for (int ks = 0; ks < 2; ++ks) {
            int kq = ks * 4 + q;
            bf16x8 af[2], bfr[4];
#pragma unroll
            for (int i = 0; i < 2; ++i)
                af[i] = *(const bf16x8*)(sA + (((kq << 6) + wr * 32 + i * 16 + rlo) << 4));
#pragma unroll
            for (int j = 0; j < 4; ++j)
                bfr[j] = *(const bf16x8*)(sB + (((kq << 7) + wc * 64 + j * 16 + rlo) << 4));
#pragma unroll
            for (int i = 0; i < 2; ++i)
#pragma unroll
                for (int j = 0; j < 4; ++j)
                    acc[i][j] = __builtin_amdgcn_mfma_f32_16x16x32_bf16(af[i], bfr[j], acc[i][j], 0, 0, 0);
        }
    }

#pragma unroll
    for (int j = 0; j < 4; ++j) {
        int col = n0 + wc * 64 + j * 16 + rlo;
        float bv = b2[col];
#pragma unroll
        for (int i = 0; i < 2; ++i) {
            int rowb = row0 + wr * 32 + i * 16 + q * 4;
#pragma unroll
            for (int rr = 0; rr < 4; ++rr) {
                float v = acc[i][j][rr] + bv;
                f[(size_t)(rowb + rr) * 512 + col] = v;
                if (col < N_SZ)
                    mub[(size_t)(rowb + rr) * N_SZ + col] = f2bf(v);
            }
        }
    }
}

// Fused: Vmu (MFMA mu@Wv rowsumsq) + epilogue (fx, logp partial per block).
// grid 128: block owns 64 rows. Stage 1: wave w computes cols w*64..+63 of
// mu@Wv for all 64 rows (flat loads, K=256); cross-wave sum in LDS.
// Stage 2: thread n handles col n, loops 64 rows; block-reduce logp partial.
__global__ __launch_bounds__(256)
void vmu_epilogue_kernel(const ushort_t* __restrict__ mub, const ushort_t* __restrict__ Wvp,
                         const float* __restrict__ f, const float* __restrict__ y,
                         const float* __restrict__ eps, const float* __restrict__ vx,
                         float* __restrict__ out, float* __restrict__ partials)
{
    __shared__ float vsum[4][64];
    __shared__ float vmu_s[64];
    __shared__ float red[4];
    const int tid = threadIdx.x;
    const int lane = tid & 63;
    const int w = tid >> 6;
    const int q = lane >> 4;
    const int rlo = lane & 15;
    const int r0 = blockIdx.x * 64;

    // ---- stage 1: Vmu via MFMA ----
    f32x4 acc[4][4];
#pragma unroll
    for (int i = 0; i < 4; ++i)
#pragma unroll
        for (int j = 0; j < 4; ++j)
            acc[i][j] = f32x4{0.f, 0.f, 0.f, 0.f};

    const ushort_t* a0 = mub + (size_t)(r0 + rlo) * N_SZ + q * 8;
    const ushort_t* b0 = Wvp + ((size_t)q * N_SZ + w * 64 + rlo) * 8;
#pragma unroll
    for (int s = 0; s < 8; ++s) {
        bf16x8 af[4], bfr[4];
#pragma unroll
        for (int i = 0; i < 4; ++i)
            af[i] = *(const bf16x8*)(a0 + i * 16 * N_SZ + s * 32);
#pragma unroll
        for (int j = 0; j < 4; ++j)
            bfr[j] = *(const bf16x8*)(b0 + s * 4 * N_SZ * 8 + j * 128);
#pragma unroll
        for (int i = 0; i < 4; ++i)
#pragma unroll
            for (int j = 0; j < 4; ++j)
                acc[i][j] = __builtin_amdgcn_mfma_f32_16x16x32_bf16(af[i], bfr[j], acc[i][j], 0, 0, 0);
    }
#pragma unroll
    for (int i = 0; i < 4; ++i) {
#pragma unroll
        for (int rr = 0; rr < 4; ++rr) {
            float s = 0.f;
#pragma unroll
            for (int j = 0; j < 4; ++j) { float v = acc[i][j][rr]; s += v * v; }
#pragma unroll
            for (int m = 1; m < 16; m <<= 1) s += __shfl_xor(s, m, 64);
            if (rlo == 0) vsum[w][i * 16 + q * 4 + rr] = s;
        }
    }
    __syncthreads();
    if (tid < 64)
        vmu_s[tid] = 1e-3f + vsum[0][tid] + vsum[1][tid] + vsum[2][tid] + vsum[3][tid];
    __syncthreads();

    // ---- stage 2: epilogue ----
    float t = 0.f;
    const int n = tid;
#pragma unroll 4
    for (int r = 0; r < 64; ++r) {
        size_t row = (size_t)(r0 + r);
        float mu = f[row * 512 + n];
        float lv = f[row * 512 + 256 + n];
        float var = expf(lv);
        float Vx = vx[row] + 1e-3f;
        float Vmu = vmu_s[r];
        float scale = fminf(BETA_F * Vx, Vmu) / Vmu;
        float mus = mu * scale;
        out[row * 256 + n] = mus + sqrtf(var) * eps[row * 256 + n];
        float d = y[row * 256 + n] - mus;
        t += lv + d * d / var;
    }
#pragma unroll
    for (int m = 32; m >= 1; m >>= 1) t += __shfl_down(t, m, 64);
    if (lane == 0) red[w] = t;
    __syncthreads();
    if (tid == 0)
        partials[blockIdx.x] = red[0] + red[1] + red[2] + red[3];
}

// sum 128 partials -> logp_y scalar. 128 threads (2 waves).
__global__ __launch_bounds__(128)
void reduce_kernel(const float* __restrict__ partials, float* __restrict__ out)
{
    int tid = threadIdx.x;
    float s = partials[tid];
#pragma unroll
    for (int m = 32; m >= 1; m >>= 1) s += __shfl_down(s, m, 64);
    __shared__ float red[2];
    if ((tid & 63) == 0) red[tid >> 6] = s;
    __syncthreads();
    if (tid == 0)
        out[(size_t)B_SZ * N_SZ] =
            0.5f * (red[0] + red[1] + (float)N_SZ * LOG2PI_F * (float)B_SZ);
}

// Conversion, fully coalesced: one thread per 8-element k-chunk.
__global__ __launch_bounds__(256)
void convert_kernel(const float* __restrict__ x, const float* __restrict__ W1,
                    const float* __restrict__ W2, const float* __restrict__ Wv,
                    ushort_t* __restrict__ xb, ushort_t* __restrict__ W1p,
                    ushort_t* __restrict__ W2p, ushort_t* __restrict__ Wvp)
{
    const int XC = 262144, W1C = 65536, W2C = 131072;
    int c = blockIdx.x * 256 + threadIdx.x;
    if (c < XC) {
        f32x4 a = *(const f32x4*)(x + (size_t)c * 8);
        f32x4 b = *(const f32x4*)(x + (size_t)c * 8 + 4);
        u16x8 o;
#pragma unroll
        for (int i = 0; i < 4; ++i) { o[i] = f2bf(a[i]); o[4 + i] = f2bf(b[i]); }
        *(u16x8*)(xb + (size_t)c * 8) = o;
    } else if (c < XC + W1C) {
        int d = c - XC;
        int ko = d >> 11, n = d & 2047;
        u16x8 o;
#pragma unroll
        for (int ki = 0; ki < 8; ++ki)
            o[ki] = f2bf(W1[(size_t)(ko * 8 + ki) * H_SZ + n]);
        *(u16x8*)(W1p + (size_t)d * 8) = o;
    } else if (c < XC + W1C + W2C) {
        int d = c - XC - W1C;
        int ko = d >> 9, n = d & 511;
        u16x8 o;
#pragma unroll
        for (int ki = 0; ki < 8; ++ki)
            o[ki] = f2bf(W2[(size_t)(ko * 8 + ki) * 512 + n]);
        *(u16x8*)(W2p + (size_t)d * 8) = o;
    } else {
        int d = c - XC - W1C - W2C;
        int ko = d >> 8, n = d & 255;
        u16x8 o;
#pragma unroll
        for (int ki = 0; ki < 8; ++ki)
            o[ki] = f2bf(Wv[(size_t)(ko * 8 + ki) * N_SZ + n]);
        *(u16x8*)(Wvp + (size_t)d * 8) = o;
    }
}

extern "C" void kernel_launch(void* const* d_in, const int* in_sizes, int n_in,
                              void* d_out, int out_size, void* d_ws, size_t ws_size,
                              hipStream_t stream)
{
    const float* x   = (const float*)d_in[0];
    const float* y   = (const float*)d_in[1];
    const float* eps = (const float*)d_in[2];
    const float* W1  = (const float*)d_in[3];
    const float* b1  = (const float*)d_in[4];
    const float* W2  = (const float*)d_in[5];
    const float* b2  = (const float*)d_in[6];
    const float* Wv  = (const float*)d_in[7];
    float* out = (float*)d_out;

    char* ws = (char*)d_ws;
    size_t off = 0;
    auto alloc = [&](size_t bytes) {
        char* p = ws + off;
        off += (bytes + 255) & ~(size_t)255;
        return p;
    };
    ushort_t* xb  = (ushort_t*)alloc((size_t)B_SZ * N_SZ * 2);
    ushort_t* W1p = (ushort_t*)alloc((size_t)N_SZ * H_SZ * 2);
    ushort_t* W2p = (ushort_t*)alloc((size_t)H_SZ * 512 * 2);
    ushort_t* Wvp = (ushort_t*)alloc((size_t)N_SZ * N_SZ * 2);
    ushort_t* h   = (ushort_t*)alloc((size_t)B_SZ * H_SZ * 2);
    float*    f   = (float*)alloc((size_t)B_SZ * 512 * 4);
    ushort_t* mub = (ushort_t*)alloc((size_t)B_SZ * N_SZ * 2);
    float*    vx  = (float*)alloc((size_t)B_SZ * 4);
    float*    partials = (float*)alloc(128 * 4);

    hipMemsetAsync(vx, 0, (size_t)B_SZ * 4, stream);

    const int TOTALC = 262144 + 65536 + 131072 + 8192;  // 466944 chunks
    convert_kernel<<<TOTALC / 256, 256, 0, stream>>>(x, W1, W2, Wv, xb, W1p, W2p, Wvp);

    // h = tanh(x@W1 + b1)  (+ fused Vx), 128x128 tiles BK=64
    gemm1_vx_kernel<<<dim3(18, B_SZ / 128), 256, 0, stream>>>(xb, W1p, Wvp, b1, h, vx);
    // f = h@W2 + b2 ; mub = bf16(mu), 64x128 tiles BK=64, XCD swizzle
    gemm2_kernel<<<512, 256, 0, stream>>>(h, W2p, b2, f, mub);
    // Vmu + epilogue fused
    vmu_epilogue_kernel<<<128, 256, 0, stream>>>(mub, Wvp, f, y, eps, vx, out, partials);
    reduce_kernel<<<1, 128, 0, stream>>>(partials, out);
}

// Round 10
// 162.382 us; speedup vs baseline: 1.2157x; 1.0782x over previous
//
#include <hip/hip_runtime.h>
#include <stdint.h>

#define B_SZ 8192
#define N_SZ 256
#define H_SZ 2048
#define LOG2PI_F 1.8378770664093453f
#define BETA_F 0.99f

typedef unsigned short ushort_t;
typedef __attribute__((ext_vector_type(8))) __bf16 bf16x8;
typedef __attribute__((ext_vector_type(4))) float f32x4;
typedef __attribute__((ext_vector_type(8))) ushort_t u16x8;

__device__ __forceinline__ ushort_t f2bf(float f) {
    unsigned int u = __float_as_uint(f);
    unsigned int r = (u + 0x7FFFu + ((u >> 16) & 1u)) >> 16;  // RNE
    return (ushort_t)r;
}

__device__ __forceinline__ float fast_tanh(float v) {
    float ex = __expf(2.0f * v);
    return 1.0f - __fdividef(2.0f, ex + 1.0f);
}

__device__ __forceinline__ void async_ld16(const void* g, const char* lds_uniform) {
    __builtin_amdgcn_global_load_lds(
        (const __attribute__((address_space(1))) void*)g,
        (__attribute__((address_space(3))) void*)lds_uniform,
        16, 0, 0);
}

// GEMM1 (tanh -> h) fused with Vx. 128x128 LDS tiles, BK=64, K=256 (4 iters).
// 1D grid 1152 with XCD swizzle: bid&7 selects XCD; each XCD sees 8 row
// stripes x all 18 col-blocks -> xb stripe fetched into that L2 once.
__global__ __launch_bounds__(256, 4)
void gemm1_vx_kernel(const ushort_t* __restrict__ xb, const ushort_t* __restrict__ W1p,
                     const ushort_t* __restrict__ Wvp, const float* __restrict__ b1,
                     ushort_t* __restrict__ h, float* __restrict__ vx)
{
    __shared__ __align__(16) char smem[32768];
    char* sA = smem;           // [8 kq][128 m][8] bf16 = 16 KB
    char* sB = smem + 16384;   // [8 kq][128 n][8] bf16 = 16 KB
    const int tid = threadIdx.x;
    const int lane = tid & 63;
    const int w = tid >> 6;
    const int q = lane >> 4;
    const int rlo = lane & 15;
    const int wr = w >> 1, wc = w & 1;

    const int bid = blockIdx.x;
    const int r8 = bid & 7;
    const int u = bid >> 3;       // 0..143
    const int cb = u % 18;        // col block
    const int tb = u / 18;        // 0..7
    const int row0 = (r8 + 8 * tb) * 128;

    const bool w1path = cb < 16;
    const int n0 = (w1path ? cb : cb - 16) * 128;
    const ushort_t* Bp = w1path ? W1p : Wvp;
    const int N = w1path ? H_SZ : N_SZ;

    f32x4 acc[4][4];
#pragma unroll
    for (int i = 0; i < 4; ++i)
#pragma unroll
        for (int j = 0; j < 4; ++j)
            acc[i][j] = f32x4{0.f, 0.f, 0.f, 0.f};

    for (int k0 = 0; k0 < N_SZ; k0 += 64) {
        __syncthreads();
#pragma unroll
        for (int r = 0; r < 4; ++r) {
            int c = r * 256 + tid;
            int kq = c >> 7, m = c & 127;
            async_ld16(xb + (size_t)(row0 + m) * N_SZ + k0 + kq * 8, sA + (c << 4));
        }
        int ko0 = k0 >> 3;
#pragma unroll
        for (int r = 0; r < 4; ++r) {
            int c = r * 256 + tid;
            int kq = c >> 7, n = c & 127;
            async_ld16(Bp + ((size_t)(ko0 + kq) * N + n0 + n) * 8, sB + (c << 4));
        }
        __syncthreads();

#pragma unroll
        for (int ks = 0; ks < 2; ++ks) {
            int kq = ks * 4 + q;
            bf16x8 af[4], bfr[4];
#pragma unroll
            for (int i = 0; i < 4; ++i)
                af[i] = *(const bf16x8*)(sA + (((kq << 7) + wr * 64 + i * 16 + rlo) << 4));
#pragma unroll
            for (int j = 0; j < 4; ++j)
                bfr[j] = *(const bf16x8*)(sB + (((kq << 7) + wc * 64 + j * 16 + rlo) << 4));
#pragma unroll
            for (int i = 0; i < 4; ++i)
#pragma unroll
                for (int j = 0; j < 4; ++j)
                    acc[i][j] = __builtin_amdgcn_mfma_f32_16x16x32_bf16(af[i], bfr[j], acc[i][j], 0, 0, 0);
        }
    }

    if (w1path) {
#pragma unroll
        for (int j = 0; j < 4; ++j) {
            int col = n0 + wc * 64 + j * 16 + rlo;
            float bv = b1[col];
#pragma unroll
            for (int i = 0; i < 4; ++i) {
                int rowb = row0 + wr * 64 + i * 16 + q * 4;
#pragma unroll
                for (int rr = 0; rr < 4; ++rr)
                    h[(size_t)(rowb + rr) * H_SZ + col] = f2bf(fast_tanh(acc[i][j][rr] + bv));
            }
        }
    } else {
#pragma unroll
        for (int i = 0; i < 4; ++i) {
#pragma unroll
            for (int rr = 0; rr < 4; ++rr) {
                float s = 0.f;
#pragma unroll
                for (int j = 0; j < 4; ++j) { float v = acc[i][j][rr]; s += v * v; }
#pragma unroll
                for (int m = 1; m < 16; m <<= 1) s += __shfl_xor(s, m, 64);
                if (rlo == 0)
                    atomicAdd(&vx[row0 + wr * 64 + i * 16 + q * 4 + rr], s);
            }
        }
    }
}

// GEMM2: f = h@W2 + b2, mub = bf16(f[:, :256]). 64x128 tiles, BK=64, K=2048.
// grid 512 (1D) with XCD swizzle.
__global__ __launch_bounds__(256, 4)
void gemm2_kernel(const ushort_t* __restrict__ h, const ushort_t* __restrict__ W2p,
                  const float* __restrict__ b2, float* __restrict__ f,
                  ushort_t* __restrict__ mub)
{
    __shared__ __align__(16) char smem[24576];
    char* sA = smem;          // [8 kq][64 m][8] bf16 = 8 KB
    char* sB = smem + 8192;   // [8 kq][128 n][8] bf16 = 16 KB
    const int tid = threadIdx.x;
    const int lane = tid & 63;
    const int w = tid >> 6;
    const int q = lane >> 4;
    const int rlo = lane & 15;
    const int wr = w >> 1, wc = w & 1;

    const int bid = blockIdx.x;
    const int r8 = bid & 7;
    const int u = bid >> 3;
    const int cb = u & 3;
    const int tb = u >> 2;
    const int row0 = (r8 + 8 * tb) * 64;
    const int n0 = cb * 128;

    f32x4 acc[2][4];
#pragma unroll
    for (int i = 0; i < 2; ++i)
#pragma unroll
        for (int j = 0; j < 4; ++j)
            acc[i][j] = f32x4{0.f, 0.f, 0.f, 0.f};

    for (int k0 = 0; k0 < H_SZ; k0 += 64) {
        __syncthreads();
#pragma unroll
        for (int r = 0; r < 2; ++r) {   // A: 512 chunks, layout [kq][m][8]
            int c = r * 256 + tid;
            int kq = c >> 6, m = c & 63;
            async_ld16(h + (size_t)(row0 + m) * H_SZ + k0 + kq * 8, sA + (c << 4));
        }
        int ko0 = k0 >> 3;
#pragma unroll
        for (int r = 0; r < 4; ++r) {   // B: 1024 chunks, layout [kq][n][8]
            int c = r * 256 + tid;
            int kq = c >> 7, n = c & 127;
            async_ld16(W2p + ((size_t)(ko0 + kq) * 512 + n0 + n) * 8, sB + (c << 4));
        }
        __syncthreads();

#pragma unroll
        for (int ks = 0; ks < 2; ++ks) {
            int kq = ks * 4 + q;
            bf16x8 af[2], bfr[4];
#pragma unroll
            for (int i = 0; i < 2; ++i)
                af[i] = *(const bf16x8*)(sA + (((kq << 6) + wr * 32 + i * 16 + rlo) << 4));
#pragma unroll
            for (int j = 0; j < 4; ++j)
                bfr[j] = *(const bf16x8*)(sB + (((kq << 7) + wc * 64 + j * 16 + rlo) << 4));
#pragma unroll
            for (int i = 0; i < 2; ++i)
#pragma unroll
                for (int j = 0; j < 4; ++j)
                    acc[i][j] = __builtin_amdgcn_mfma_f32_16x16x32_bf16(af[i], bfr[j], acc[i][j], 0, 0, 0);
        }
    }

#pragma unroll
    for (int j = 0; j < 4; ++j) {
        int col = n0 + wc * 64 + j * 16 + rlo;
        float bv = b2[col];
#pragma unroll
        for (int i = 0; i < 2; ++i) {
            int rowb = row0 + wr * 32 + i * 16 + q * 4;
#pragma unroll
            for (int rr = 0; rr < 4; ++rr) {
                float v = acc[i][j][rr] + bv;
                f[(size_t)(rowb + rr) * 512 + col] = v;
                if (col < N_SZ)
                    mub[(size_t)(rowb + rr) * N_SZ + col] = f2bf(v);
            }
        }
    }
}

// Fused Vmu + epilogue, 512 blocks x 16 rows (2 blocks/CU).
// Stage 1: wave w computes 16 rows x cols [w*64, w*64+63] of mu@Wv (flat
// loads, K=256), rowsumsq -> LDS; sum over waves -> vmu_s[16].
// Stage 2: thread n = col, loops 16 rows; per-block logp partial.
__global__ __launch_bounds__(256)
void vmu_epilogue_kernel(const ushort_t* __restrict__ mub, const ushort_t* __restrict__ Wvp,
                         const float* __restrict__ f, const float* __restrict__ y,
                         const float* __restrict__ eps, const float* __restrict__ vx,
                         float* __restrict__ out, float* __restrict__ partials)
{
    __shared__ float vsum[4][16];
    __shared__ float vmu_s[16];
    __shared__ float red[4];
    const int tid = threadIdx.x;
    const int lane = tid & 63;
    const int w = tid >> 6;
    const int q = lane >> 4;
    const int rlo = lane & 15;
    const int r0 = blockIdx.x * 16;

    // ---- stage 1: Vmu via MFMA (16x64 tile per wave) ----
    f32x4 acc[4];
#pragma unroll
    for (int j = 0; j < 4; ++j)
        acc[j] = f32x4{0.f, 0.f, 0.f, 0.f};

    const ushort_t* a0 = mub + (size_t)(r0 + rlo) * N_SZ + q * 8;
    const ushort_t* b0 = Wvp + ((size_t)q * N_SZ + w * 64 + rlo) * 8;
#pragma unroll
    for (int s = 0; s < 8; ++s) {
        bf16x8 af = *(const bf16x8*)(a0 + s * 32);
        bf16x8 bfr[4];
#pragma unroll
        for (int j = 0; j < 4; ++j)
            bfr[j] = *(const bf16x8*)(b0 + s * 4 * N_SZ * 8 + j * 128);
#pragma unroll
        for (int j = 0; j < 4; ++j)
            acc[j] = __builtin_amdgcn_mfma_f32_16x16x32_bf16(af, bfr[j], acc[j], 0, 0, 0);
    }
#pragma unroll
    for (int rr = 0; rr < 4; ++rr) {
        float s = 0.f;
#pragma unroll
        for (int j = 0; j < 4; ++j) { float v = acc[j][rr]; s += v * v; }
#pragma unroll
        for (int m = 1; m < 16; m <<= 1) s += __shfl_xor(s, m, 64);
        if (rlo == 0) vsum[w][q * 4 + rr] = s;
    }
    __syncthreads();
    if (tid < 16)
        vmu_s[tid] = 1e-3f + vsum[0][tid] + vsum[1][tid] + vsum[2][tid] + vsum[3][tid];
    __syncthreads();

    // ---- stage 2: epilogue over 16 rows ----
    float t = 0.f;
    const int n = tid;
#pragma unroll 4
    for (int r = 0; r < 16; ++r) {
        size_t row = (size_t)(r0 + r);
        float mu = f[row * 512 + n];
        float lv = f[row * 512 + 256 + n];
        float var = expf(lv);
        float Vx = vx[row] + 1e-3f;
        float Vmu = vmu_s[r];
        float scale = fminf(BETA_F * Vx, Vmu) / Vmu;
        float mus = mu * scale;
        out[row * 256 + n] = mus + sqrtf(var) * eps[row * 256 + n];
        float d = y[row * 256 + n] - mus;
        t += lv + d * d / var;
    }
#pragma unroll
    for (int m = 32; m >= 1; m >>= 1) t += __shfl_down(t, m, 64);
    if (lane == 0) red[w] = t;
    __syncthreads();
    if (tid == 0)
        partials[blockIdx.x] = red[0] + red[1] + red[2] + red[3];
}

// sum 512 partials -> logp_y scalar.
__global__ __launch_bounds__(256)
void reduce_kernel(const float* __restrict__ partials, float* __restrict__ out)
{
    int tid = threadIdx.x;
    float s = partials[tid] + partials[tid + 256];
#pragma unroll
    for (int m = 32; m >= 1; m >>= 1) s += __shfl_down(s, m, 64);
    __shared__ float red[4];
    if ((tid & 63) == 0) red[tid >> 6] = s;
    __syncthreads();
    if (tid == 0)
        out[(size_t)B_SZ * N_SZ] =
            0.5f * (red[0] + red[1] + red[2] + red[3] +
                    (float)N_SZ * LOG2PI_F * (float)B_SZ);
}

// Conversion, fully coalesced: one thread per 8-element k-chunk.
__global__ __launch_bounds__(256)
void convert_kernel(const float* __restrict__ x, const float* __restrict__ W1,
                    const float* __restrict__ W2, const float* __restrict__ Wv,
                    ushort_t* __restrict__ xb, ushort_t* __restrict__ W1p,
                    ushort_t* __restrict__ W2p, ushort_t* __restrict__ Wvp)
{
    const int XC = 262144, W1C = 65536, W2C = 131072;
    int c = blockIdx.x * 256 + threadIdx.x;
    if (c < XC) {
        f32x4 a = *(const f32x4*)(x + (size_t)c * 8);
        f32x4 b = *(const f32x4*)(x + (size_t)c * 8 + 4);
        u16x8 o;
#pragma unroll
        for (int i = 0; i < 4; ++i) { o[i] = f2bf(a[i]); o[4 + i] = f2bf(b[i]); }
        *(u16x8*)(xb + (size_t)c * 8) = o;
    } else if (c < XC + W1C) {
        int d = c - XC;
        int ko = d >> 11, n = d & 2047;
        u16x8 o;
#pragma unroll
        for (int ki = 0; ki < 8; ++ki)
            o[ki] = f2bf(W1[(size_t)(ko * 8 + ki) * H_SZ + n]);
        *(u16x8*)(W1p + (size_t)d * 8) = o;
    } else if (c < XC + W1C + W2C) {
        int d = c - XC - W1C;
        int ko = d >> 9, n = d & 511;
        u16x8 o;
#pragma unroll
        for (int ki = 0; ki < 8; ++ki)
            o[ki] = f2bf(W2[(size_t)(ko * 8 + ki) * 512 + n]);
        *(u16x8*)(W2p + (size_t)d * 8) = o;
    } else {
        int d = c - XC - W1C - W2C;
        int ko = d >> 8, n = d & 255;
        u16x8 o;
#pragma unroll
        for (int ki = 0; ki < 8; ++ki)
            o[ki] = f2bf(Wv[(size_t)(ko * 8 + ki) * N_SZ + n]);
        *(u16x8*)(Wvp + (size_t)d * 8) = o;
    }
}

extern "C" void kernel_launch(void* const* d_in, const int* in_sizes, int n_in,
                              void* d_out, int out_size, void* d_ws, size_t ws_size,
                              hipStream_t stream)
{
    const float* x   = (const float*)d_in[0];
    const float* y   = (const float*)d_in[1];
    const float* eps = (const float*)d_in[2];
    const float* W1  = (const float*)d_in[3];
    const float* b1  = (const float*)d_in[4];
    const float* W2  = (const float*)d_in[5];
    const float* b2  = (const float*)d_in[6];
    const float* Wv  = (const float*)d_in[7];
    float* out = (float*)d_out;

    char* ws = (char*)d_ws;
    size_t off = 0;
    auto alloc = [&](size_t bytes) {
        char* p = ws + off;
        off += (bytes + 255) & ~(size_t)255;
        return p;
    };
    ushort_t* xb  = (ushort_t*)alloc((size_t)B_SZ * N_SZ * 2);
    ushort_t* W1p = (ushort_t*)alloc((size_t)N_SZ * H_SZ * 2);
    ushort_t* W2p = (ushort_t*)alloc((size_t)H_SZ * 512 * 2);
    ushort_t* Wvp = (ushort_t*)alloc((size_t)N_SZ * N_SZ * 2);
    ushort_t* h   = (ushort_t*)alloc((size_t)B_SZ * H_SZ * 2);
    float*    f   = (float*)alloc((size_t)B_SZ * 512 * 4);
    ushort_t* mub = (ushort_t*)alloc((size_t)B_SZ * N_SZ * 2);
    float*    vx  = (float*)alloc((size_t)B_SZ * 4);
    float*    partials = (float*)alloc(512 * 4);

    hipMemsetAsync(vx, 0, (size_t)B_SZ * 4, stream);

    const int TOTALC = 262144 + 65536 + 131072 + 8192;  // 466944 chunks
    convert_kernel<<<TOTALC / 256, 256, 0, stream>>>(x, W1, W2, Wv, xb, W1p, W2p, Wvp);

    // h = tanh(x@W1 + b1)  (+ fused Vx), XCD-swizzled 1D grid
    gemm1_vx_kernel<<<1152, 256, 0, stream>>>(xb, W1p, Wvp, b1, h, vx);
    // f = h@W2 + b2 ; mub = bf16(mu)
    gemm2_kernel<<<512, 256, 0, stream>>>(h, W2p, b2, f, mub);
    // Vmu + epilogue fused, 512 blocks
    vmu_epilogue_kernel<<<512, 256, 0, stream>>>(mub, Wvp, f, y, eps, vx, out, partials);
    reduce_kernel<<<1, 256, 0, stream>>>(partials, out);
}

// Round 11
// 162.294 us; speedup vs baseline: 1.2163x; 1.0005x over previous
//
#include <hip/hip_runtime.h>
#include <stdint.h>

#define B_SZ 8192
#define N_SZ 256
#define H_SZ 2048
#define LOG2PI_F 1.8378770664093453f
#define BETA_F 0.99f

typedef unsigned short ushort_t;
typedef __attribute__((ext_vector_type(8))) __bf16 bf16x8;
typedef __attribute__((ext_vector_type(4))) float f32x4;
typedef __attribute__((ext_vector_type(8))) ushort_t u16x8;

__device__ __forceinline__ ushort_t f2bf(float f) {
    unsigned int u = __float_as_uint(f);
    unsigned int r = (u + 0x7FFFu + ((u >> 16) & 1u)) >> 16;  // RNE
    return (ushort_t)r;
}

__device__ __forceinline__ float fast_tanh(float v) {
    float ex = __expf(2.0f * v);
    return 1.0f - __fdividef(2.0f, ex + 1.0f);
}

__device__ __forceinline__ void async_ld16(const void* g, const char* lds_uniform) {
    __builtin_amdgcn_global_load_lds(
        (const __attribute__((address_space(1))) void*)g,
        (__attribute__((address_space(3))) void*)lds_uniform,
        16, 0, 0);
}

// GEMM1 (tanh -> h) fused with Vx. 128x128 tiles, BK=128 (2 K-iters).
// 1D grid 1152, XCD swizzle. Vx partials -> vxp (no atomics).
__global__ __launch_bounds__(256, 2)
void gemm1_vx_kernel(const ushort_t* __restrict__ xb, const ushort_t* __restrict__ W1p,
                     const ushort_t* __restrict__ Wvp, const float* __restrict__ b1,
                     ushort_t* __restrict__ h, float* __restrict__ vxp)
{
    __shared__ __align__(16) char smem[65536];
    char* sA = smem;           // [16 kq][128 m][8] bf16 = 32 KB
    char* sB = smem + 32768;   // [16 kq][128 n][8] bf16 = 32 KB
    const int tid = threadIdx.x;
    const int lane = tid & 63;
    const int w = tid >> 6;
    const int q = lane >> 4;
    const int rlo = lane & 15;
    const int wr = w >> 1, wc = w & 1;

    const int bid = blockIdx.x;
    const int r8 = bid & 7;
    const int u = bid >> 3;       // 0..143
    const int cb = u % 18;
    const int tb = u / 18;        // 0..7
    const int row0 = (r8 + 8 * tb) * 128;

    const bool w1path = cb < 16;
    const int n0 = (w1path ? cb : cb - 16) * 128;
    const ushort_t* Bp = w1path ? W1p : Wvp;
    const int N = w1path ? H_SZ : N_SZ;

    f32x4 acc[4][4];
#pragma unroll
    for (int i = 0; i < 4; ++i)
#pragma unroll
        for (int j = 0; j < 4; ++j)
            acc[i][j] = f32x4{0.f, 0.f, 0.f, 0.f};

    for (int k0 = 0; k0 < N_SZ; k0 += 128) {
        __syncthreads();
#pragma unroll
        for (int r = 0; r < 8; ++r) {
            int c = r * 256 + tid;
            int kq = c >> 7, m = c & 127;
            async_ld16(xb + (size_t)(row0 + m) * N_SZ + k0 + kq * 8, sA + (c << 4));
        }
        int ko0 = k0 >> 3;
#pragma unroll
        for (int r = 0; r < 8; ++r) {
            int c = r * 256 + tid;
            int kq = c >> 7, n = c & 127;
            async_ld16(Bp + ((size_t)(ko0 + kq) * N + n0 + n) * 8, sB + (c << 4));
        }
        __syncthreads();

#pragma unroll
        for (int ks = 0; ks < 4; ++ks) {
            int kq = ks * 4 + q;
            bf16x8 af[4], bfr[4];
#pragma unroll
            for (int i = 0; i < 4; ++i)
                af[i] = *(const bf16x8*)(sA + (((kq << 7) + wr * 64 + i * 16 + rlo) << 4));
#pragma unroll
            for (int j = 0; j < 4; ++j)
                bfr[j] = *(const bf16x8*)(sB + (((kq << 7) + wc * 64 + j * 16 + rlo) << 4));
#pragma unroll
            for (int i = 0; i < 4; ++i)
#pragma unroll
                for (int j = 0; j < 4; ++j)
                    acc[i][j] = __builtin_amdgcn_mfma_f32_16x16x32_bf16(af[i], bfr[j], acc[i][j], 0, 0, 0);
        }
    }

    if (w1path) {
#pragma unroll
        for (int j = 0; j < 4; ++j) {
            int col = n0 + wc * 64 + j * 16 + rlo;
            float bv = b1[col];
#pragma unroll
            for (int i = 0; i < 4; ++i) {
                int rowb = row0 + wr * 64 + i * 16 + q * 4;
#pragma unroll
                for (int rr = 0; rr < 4; ++rr)
                    h[(size_t)(rowb + rr) * H_SZ + col] = f2bf(fast_tanh(acc[i][j][rr] + bv));
            }
        }
    } else {
        // Vx partial for col-half (n0>>7): plain store, no atomics
        float* vdst = vxp + (n0 >> 7) * B_SZ;
#pragma unroll
        for (int i = 0; i < 4; ++i) {
#pragma unroll
            for (int rr = 0; rr < 4; ++rr) {
                float s = 0.f;
#pragma unroll
                for (int j = 0; j < 4; ++j) { float v = acc[i][j][rr]; s += v * v; }
#pragma unroll
                for (int m = 1; m < 16; m <<= 1) s += __shfl_xor(s, m, 64);
                if (rlo == 0)
                    vdst[row0 + wr * 64 + i * 16 + q * 4 + rr] = s;
            }
        }
    }
}

// GEMM2: f = h@W2 + b2, mub = bf16(f[:, :256]). 64x128 tiles, BK=128 (16 iters).
// grid 512, XCD swizzle.
__global__ __launch_bounds__(256, 2)
void gemm2_kernel(const ushort_t* __restrict__ h, const ushort_t* __restrict__ W2p,
                  const float* __restrict__ b2, float* __restrict__ f,
                  ushort_t* __restrict__ mub)
{
    __shared__ __align__(16) char smem[49152];
    char* sA = smem;           // [16 kq][64 m][8] bf16 = 16 KB
    char* sB = smem + 16384;   // [16 kq][128 n][8] bf16 = 32 KB
    const int tid = threadIdx.x;
    const int lane = tid & 63;
    const int w = tid >> 6;
    const int q = lane >> 4;
    const int rlo = lane & 15;
    const int wr = w >> 1, wc = w & 1;

    const int bid = blockIdx.x;
    const int r8 = bid & 7;
    const int u = bid >> 3;
    const int cb = u & 3;
    const int tb = u >> 2;
    const int row0 = (r8 + 8 * tb) * 64;
    const int n0 = cb * 128;

    f32x4 acc[2][4];
#pragma unroll
    for (int i = 0; i < 2; ++i)
#pragma unroll
        for (int j = 0; j < 4; ++j)
            acc[i][j] = f32x4{0.f, 0.f, 0.f, 0.f};

    for (int k0 = 0; k0 < H_SZ; k0 += 128) {
        __syncthreads();
#pragma unroll
        for (int r = 0; r < 4; ++r) {   // A: 1024 chunks, layout [kq][m][8]
            int c = r * 256 + tid;
            int kq = c >> 6, m = c & 63;
            async_ld16(h + (size_t)(row0 + m) * H_SZ + k0 + kq * 8, sA + (c << 4));
        }
        int ko0 = k0 >> 3;
#pragma unroll
        for (int r = 0; r < 8; ++r) {   // B: 2048 chunks, layout [kq][n][8]
            int c = r * 256 + tid;
            int kq = c >> 7, n = c & 127;
            async_ld16(W2p + ((size_t)(ko0 + kq) * 512 + n0 + n) * 8, sB + (c << 4));
        }
        __syncthreads();

#pragma unroll
        for (int ks = 0; ks < 4; ++ks) {
            int kq = ks * 4 + q;
            bf16x8 af[2], bfr[4];
#pragma unroll
            for (int i = 0; i < 2; ++i)
                af[i] = *(const bf16x8*)(sA + (((kq << 6) + wr * 32 + i * 16 + rlo) << 4));
#pragma unroll
            for (int j = 0; j < 4; ++j)
                bfr[j] = *(const bf16x8*)(sB + (((kq << 7) + wc * 64 + j * 16 + rlo) << 4));
#pragma unroll
            for (int i = 0; i < 2; ++i)
#pragma unroll
                for (int j = 0; j < 4; ++j)
                    acc[i][j] = __builtin_amdgcn_mfma_f32_16x16x32_bf16(af[i], bfr[j], acc[i][j], 0, 0, 0);
        }
    }

#pragma unroll
    for (int j = 0; j < 4; ++j) {
        int col = n0 + wc * 64 + j * 16 + rlo;
        float bv = b2[col];
#pragma unroll
        for (int i = 0; i < 2; ++i) {
            int rowb = row0 + wr * 32 + i * 16 + q * 4;
#pragma unroll
            for (int rr = 0; rr < 4; ++rr) {
                float v = acc[i][j][rr] + bv;
                f[(size_t)(rowb + rr) * 512 + col] = v;
                if (col < N_SZ)
                    mub[(size_t)(rowb + rr) * N_SZ + col] = f2bf(v);
            }
        }
    }
}

// Fused Vmu + epilogue, 512 blocks x 16 rows.
__global__ __launch_bounds__(256)
void vmu_epilogue_kernel(const ushort_t* __restrict__ mub, const ushort_t* __restrict__ Wvp,
                         const float* __restrict__ f, const float* __restrict__ y,
                         const float* __restrict__ eps, const float* __restrict__ vxp,
                         float* __restrict__ out, float* __restrict__ partials)
{
    __shared__ float vsum[4][16];
    __shared__ float vmu_s[16];
    __shared__ float red[4];
    const int tid = threadIdx.x;
    const int lane = tid & 63;
    const int w = tid >> 6;
    const int q = lane >> 4;
    const int rlo = lane & 15;
    const int r0 = blockIdx.x * 16;

    // ---- stage 1: Vmu via MFMA (16x64 tile per wave) ----
    f32x4 acc[4];
#pragma unroll
    for (int j = 0; j < 4; ++j)
        acc[j] = f32x4{0.f, 0.f, 0.f, 0.f};

    const ushort_t* a0 = mub + (size_t)(r0 + rlo) * N_SZ + q * 8;
    const ushort_t* b0 = Wvp + ((size_t)q * N_SZ + w * 64 + rlo) * 8;
#pragma unroll
    for (int s = 0; s < 8; ++s) {
        bf16x8 af = *(const bf16x8*)(a0 + s * 32);
        bf16x8 bfr[4];
#pragma unroll
        for (int j = 0; j < 4; ++j)
            bfr[j] = *(const bf16x8*)(b0 + s * 4 * N_SZ * 8 + j * 128);
#pragma unroll
        for (int j = 0; j < 4; ++j)
            acc[j] = __builtin_amdgcn_mfma_f32_16x16x32_bf16(af, bfr[j], acc[j], 0, 0, 0);
    }
#pragma unroll
    for (int rr = 0; rr < 4; ++rr) {
        float s = 0.f;
#pragma unroll
        for (int j = 0; j < 4; ++j) { float v = acc[j][rr]; s += v * v; }
#pragma unroll
        for (int m = 1; m < 16; m <<= 1) s += __shfl_xor(s, m, 64);
        if (rlo == 0) vsum[w][q * 4 + rr] = s;
    }
    __syncthreads();
    if (tid < 16)
        vmu_s[tid] = 1e-3f + vsum[0][tid] + vsum[1][tid] + vsum[2][tid] + vsum[3][tid];
    __syncthreads();

    // ---- stage 2: epilogue over 16 rows ----
    float t = 0.f;
    const int n = tid;
#pragma unroll 4
    for (int r = 0; r < 16; ++r) {
        size_t row = (size_t)(r0 + r);
        float mu = f[row * 512 + n];
        float lv = f[row * 512 + 256 + n];
        float var = expf(lv);
        float Vx = vxp[row] + vxp[B_SZ + row] + 1e-3f;
        float Vmu = vmu_s[r];
        float scale = fminf(BETA_F * Vx, Vmu) / Vmu;
        float mus = mu * scale;
        out[row * 256 + n] = mus + sqrtf(var) * eps[row * 256 + n];
        float d = y[row * 256 + n] - mus;
        t += lv + d * d / var;
    }
#pragma unroll
    for (int m = 32; m >= 1; m >>= 1) t += __shfl_down(t, m, 64);
    if (lane == 0) red[w] = t;
    __syncthreads();
    if (tid == 0)
        partials[blockIdx.x] = red[0] + red[1] + red[2] + red[3];
}

// sum 512 partials -> logp_y scalar.
__global__ __launch_bounds__(256)
void reduce_kernel(const float* __restrict__ partials, float* __restrict__ out)
{
    int tid = threadIdx.x;
    float s = partials[tid] + partials[tid + 256];
#pragma unroll
    for (int m = 32; m >= 1; m >>= 1) s += __shfl_down(s, m, 64);
    __shared__ float red[4];
    if ((tid & 63) == 0) red[tid >> 6] = s;
    __syncthreads();
    if (tid == 0)
        out[(size_t)B_SZ * N_SZ] =
            0.5f * (red[0] + red[1] + red[2] + red[3] +
                    (float)N_SZ * LOG2PI_F * (float)B_SZ);
}

// Conversion, fully coalesced: one thread per 8-element k-chunk.
__global__ __launch_bounds__(256)
void convert_kernel(const float* __restrict__ x, const float* __restrict__ W1,
                    const float* __restrict__ W2, const float* __restrict__ Wv,
                    ushort_t* __restrict__ xb, ushort_t* __restrict__ W1p,
                    ushort_t* __restrict__ W2p, ushort_t* __restrict__ Wvp)
{
    const int XC = 262144, W1C = 65536, W2C = 131072;
    int c = blockIdx.x * 256 + threadIdx.x;
    if (c < XC) {
        f32x4 a = *(const f32x4*)(x + (size_t)c * 8);
        f32x4 b = *(const f32x4*)(x + (size_t)c * 8 + 4);
        u16x8 o;
#pragma unroll
        for (int i = 0; i < 4; ++i) { o[i] = f2bf(a[i]); o[4 + i] = f2bf(b[i]); }
        *(u16x8*)(xb + (size_t)c * 8) = o;
    } else if (c < XC + W1C) {
        int d = c - XC;
        int ko = d >> 11, n = d & 2047;
        u16x8 o;
#pragma unroll
        for (int ki = 0; ki < 8; ++ki)
            o[ki] = f2bf(W1[(size_t)(ko * 8 + ki) * H_SZ + n]);
        *(u16x8*)(W1p + (size_t)d * 8) = o;
    } else if (c < XC + W1C + W2C) {
        int d = c - XC - W1C;
        int ko = d >> 9, n = d & 511;
        u16x8 o;
#pragma unroll
        for (int ki = 0; ki < 8; ++ki)
            o[ki] = f2bf(W2[(size_t)(ko * 8 + ki) * 512 + n]);
        *(u16x8*)(W2p + (size_t)d * 8) = o;
    } else {
        int d = c - XC - W1C - W2C;
        int ko = d >> 8, n = d & 255;
        u16x8 o;
#pragma unroll
        for (int ki = 0; ki < 8; ++ki)
            o[ki] = f2bf(Wv[(size_t)(ko * 8 + ki) * N_SZ + n]);
        *(u16x8*)(Wvp + (size_t)d * 8) = o;
    }
}

extern "C" void kernel_launch(void* const* d_in, const int* in_sizes, int n_in,
                              void* d_out, int out_size, void* d_ws, size_t ws_size,
                              hipStream_t stream)
{
    const float* x   = (const float*)d_in[0];
    const float* y   = (const float*)d_in[1];
    const float* eps = (const float*)d_in[2];
    const float* W1  = (const float*)d_in[3];
    const float* b1  = (const float*)d_in[4];
    const float* W2  = (const float*)d_in[5];
    const float* b2  = (const float*)d_in[6];
    const float* Wv  = (const float*)d_in[7];
    float* out = (float*)d_out;

    char* ws = (char*)d_ws;
    size_t off = 0;
    auto alloc = [&](size_t bytes) {
        char* p = ws + off;
        off += (bytes + 255) & ~(size_t)255;
        return p;
    };
    ushort_t* xb  = (ushort_t*)alloc((size_t)B_SZ * N_SZ * 2);
    ushort_t* W1p = (ushort_t*)alloc((size_t)N_SZ * H_SZ * 2);
    ushort_t* W2p = (ushort_t*)alloc((size_t)H_SZ * 512 * 2);
    ushort_t* Wvp = (ushort_t*)alloc((size_t)N_SZ * N_SZ * 2);
    ushort_t* h   = (ushort_t*)alloc((size_t)B_SZ * H_SZ * 2);
    float*    f   = (float*)alloc((size_t)B_SZ * 512 * 4);
    ushort_t* mub = (ushort_t*)alloc((size_t)B_SZ * N_SZ * 2);
    float*    vxp = (float*)alloc((size_t)2 * B_SZ * 4);
    float*    partials = (float*)alloc(512 * 4);

    const int TOTALC = 262144 + 65536 + 131072 + 8192;  // 466944 chunks
    convert_kernel<<<TOTALC / 256, 256, 0, stream>>>(x, W1, W2, Wv, xb, W1p, W2p, Wvp);

    // h = tanh(x@W1 + b1)  (+ fused Vx partials), BK=128
    gemm1_vx_kernel<<<1152, 256, 0, stream>>>(xb, W1p, Wvp, b1, h, vxp);
    // f = h@W2 + b2 ; mub = bf16(mu), BK=128
    gemm2_kernel<<<512, 256, 0, stream>>>(h, W2p, b2, f, mub);
    // Vmu + epilogue fused, 512 blocks
    vmu_epilogue_kernel<<<512, 256, 0, stream>>>(mub, Wvp, f, y, eps, vxp, out, partials);
    reduce_kernel<<<1, 256, 0, stream>>>(partials, out);
}

// Round 12
// 160.285 us; speedup vs baseline: 1.2316x; 1.0125x over previous
//
#include <hip/hip_runtime.h>
#include <stdint.h>

#define B_SZ 8192
#define N_SZ 256
#define H_SZ 2048
#define LOG2PI_F 1.8378770664093453f
#define BETA_F 0.99f

typedef unsigned short ushort_t;
typedef __attribute__((ext_vector_type(8))) __bf16 bf16x8;
typedef __attribute__((ext_vector_type(4))) float f32x4;
typedef __attribute__((ext_vector_type(8))) ushort_t u16x8;

__device__ __forceinline__ ushort_t f2bf(float f) {
    unsigned int u = __float_as_uint(f);
    unsigned int r = (u + 0x7FFFu + ((u >> 16) & 1u)) >> 16;  // RNE
    return (ushort_t)r;
}

__device__ __forceinline__ float fast_tanh(float v) {
    float ex = __expf(2.0f * v);
    return 1.0f - __fdividef(2.0f, ex + 1.0f);
}

__device__ __forceinline__ void async_ld16(const void* g, const char* lds_uniform) {
    __builtin_amdgcn_global_load_lds(
        (const __attribute__((address_space(1))) void*)g,
        (__attribute__((address_space(3))) void*)lds_uniform,
        16, 0, 0);
}

// GEMM1 (tanh -> h) fused with Vx. 128x128 tiles, BK=64 (4 K-iters) —
// measured best (R10): 32 KB LDS, 4 blocks/CU. 1D grid 1152, XCD swizzle.
// Vx partials -> vxp (no atomics).
__global__ __launch_bounds__(256, 4)
void gemm1_vx_kernel(const ushort_t* __restrict__ xb, const ushort_t* __restrict__ W1p,
                     const ushort_t* __restrict__ Wvp, const float* __restrict__ b1,
                     ushort_t* __restrict__ h, float* __restrict__ vxp)
{
    __shared__ __align__(16) char smem[32768];
    char* sA = smem;           // [8 kq][128 m][8] bf16 = 16 KB
    char* sB = smem + 16384;   // [8 kq][128 n][8] bf16 = 16 KB
    const int tid = threadIdx.x;
    const int lane = tid & 63;
    const int w = tid >> 6;
    const int q = lane >> 4;
    const int rlo = lane & 15;
    const int wr = w >> 1, wc = w & 1;

    const int bid = blockIdx.x;
    const int r8 = bid & 7;
    const int u = bid >> 3;       // 0..143
    const int cb = u % 18;
    const int tb = u / 18;        // 0..7
    const int row0 = (r8 + 8 * tb) * 128;

    const bool w1path = cb < 16;
    const int n0 = (w1path ? cb : cb - 16) * 128;
    const ushort_t* Bp = w1path ? W1p : Wvp;
    const int N = w1path ? H_SZ : N_SZ;

    f32x4 acc[4][4];
#pragma unroll
    for (int i = 0; i < 4; ++i)
#pragma unroll
        for (int j = 0; j < 4; ++j)
            acc[i][j] = f32x4{0.f, 0.f, 0.f, 0.f};

    for (int k0 = 0; k0 < N_SZ; k0 += 64) {
        __syncthreads();
#pragma unroll
        for (int r = 0; r < 4; ++r) {
            int c = r * 256 + tid;
            int kq = c >> 7, m = c & 127;
            async_ld16(xb + (size_t)(row0 + m) * N_SZ + k0 + kq * 8, sA + (c << 4));
        }
        int ko0 = k0 >> 3;
#pragma unroll
        for (int r = 0; r < 4; ++r) {
            int c = r * 256 + tid;
            int kq = c >> 7, n = c & 127;
            async_ld16(Bp + ((size_t)(ko0 + kq) * N + n0 + n) * 8, sB + (c << 4));
        }
        __syncthreads();

#pragma unroll
        for (int ks = 0; ks < 2; ++ks) {
            int kq = ks * 4 + q;
            bf16x8 af[4], bfr[4];
#pragma unroll
            for (int i = 0; i < 4; ++i)
                af[i] = *(const bf16x8*)(sA + (((kq << 7) + wr * 64 + i * 16 + rlo) << 4));
#pragma unroll
            for (int j = 0; j < 4; ++j)
                bfr[j] = *(const bf16x8*)(sB + (((kq << 7) + wc * 64 + j * 16 + rlo) << 4));
#pragma unroll
            for (int i = 0; i < 4; ++i)
#pragma unroll
                for (int j = 0; j < 4; ++j)
                    acc[i][j] = __builtin_amdgcn_mfma_f32_16x16x32_bf16(af[i], bfr[j], acc[i][j], 0, 0, 0);
        }
    }

    if (w1path) {
#pragma unroll
        for (int j = 0; j < 4; ++j) {
            int col = n0 + wc * 64 + j * 16 + rlo;
            float bv = b1[col];
#pragma unroll
            for (int i = 0; i < 4; ++i) {
                int rowb = row0 + wr * 64 + i * 16 + q * 4;
#pragma unroll
                for (int rr = 0; rr < 4; ++rr)
                    h[(size_t)(rowb + rr) * H_SZ + col] = f2bf(fast_tanh(acc[i][j][rr] + bv));
            }
        }
    } else {
        // Vx partial for col-half (n0>>7): plain store, no atomics
        float* vdst = vxp + (n0 >> 7) * B_SZ;
#pragma unroll
        for (int i = 0; i < 4; ++i) {
#pragma unroll
            for (int rr = 0; rr < 4; ++rr) {
                float s = 0.f;
#pragma unroll
                for (int j = 0; j < 4; ++j) { float v = acc[i][j][rr]; s += v * v; }
#pragma unroll
                for (int m = 1; m < 16; m <<= 1) s += __shfl_xor(s, m, 64);
                if (rlo == 0)
                    vdst[row0 + wr * 64 + i * 16 + q * 4 + rr] = s;
            }
        }
    }
}

// GEMM2: f = h@W2 + b2, mub = bf16(f[:, :256]). 64x128 tiles, BK=128 (16 iters)
// — measured best (R11). grid 512, XCD swizzle.
__global__ __launch_bounds__(256, 2)
void gemm2_kernel(const ushort_t* __restrict__ h, const ushort_t* __restrict__ W2p,
                  const float* __restrict__ b2, float* __restrict__ f,
                  ushort_t* __restrict__ mub)
{
    __shared__ __align__(16) char smem[49152];
    char* sA = smem;           // [16 kq][64 m][8] bf16 = 16 KB
    char* sB = smem + 16384;   // [16 kq][128 n][8] bf16 = 32 KB
    const int tid = threadIdx.x;
    const int lane = tid & 63;
    const int w = tid >> 6;
    const int q = lane >> 4;
    const int rlo = lane & 15;
    const int wr = w >> 1, wc = w & 1;

    const int bid = blockIdx.x;
    const int r8 = bid & 7;
    const int u = bid >> 3;
    const int cb = u & 3;
    const int tb = u >> 2;
    const int row0 = (r8 + 8 * tb) * 64;
    const int n0 = cb * 128;

    f32x4 acc[2][4];
#pragma unroll
    for (int i = 0; i < 2; ++i)
#pragma unroll
        for (int j = 0; j < 4; ++j)
            acc[i][j] = f32x4{0.f, 0.f, 0.f, 0.f};

    for (int k0 = 0; k0 < H_SZ; k0 += 128) {
        __syncthreads();
#pragma unroll
        for (int r = 0; r < 4; ++r) {   // A: 1024 chunks, layout [kq][m][8]
            int c = r * 256 + tid;
            int kq = c >> 6, m = c & 63;
            async_ld16(h + (size_t)(row0 + m) * H_SZ + k0 + kq * 8, sA + (c << 4));
        }
        int ko0 = k0 >> 3;
#pragma unroll
        for (int r = 0; r < 8; ++r) {   // B: 2048 chunks, layout [kq][n][8]
            int c = r * 256 + tid;
            int kq = c >> 7, n = c & 127;
            async_ld16(W2p + ((size_t)(ko0 + kq) * 512 + n0 + n) * 8, sB + (c << 4));
        }
        __syncthreads();

#pragma unroll
        for (int ks = 0; ks < 4; ++ks) {
            int kq = ks * 4 + q;
            bf16x8 af[2], bfr[4];
#pragma unroll
            for (int i = 0; i < 2; ++i)
                af[i] = *(const bf16x8*)(sA + (((kq << 6) + wr * 32 + i * 16 + rlo) << 4));
#pragma unroll
            for (int j = 0; j < 4; ++j)
                bfr[j] = *(const bf16x8*)(sB + (((kq << 7) + wc * 64 + j * 16 + rlo) << 4));
#pragma unroll
            for (int i = 0; i < 2; ++i)
#pragma unroll
                for (int j = 0; j < 4; ++j)
                    acc[i][j] = __builtin_amdgcn_mfma_f32_16x16x32_bf16(af[i], bfr[j], acc[i][j], 0, 0, 0);
        }
    }

#pragma unroll
    for (int j = 0; j < 4; ++j) {
        int col = n0 + wc * 64 + j * 16 + rlo;
        float bv = b2[col];
#pragma unroll
        for (int i = 0; i < 2; ++i) {
            int rowb = row0 + wr * 32 + i * 16 + q * 4;
#pragma unroll
            for (int rr = 0; rr < 4; ++rr) {
                float v = acc[i][j][rr] + bv;
                f[(size_t)(rowb + rr) * 512 + col] = v;
                if (col < N_SZ)
                    mub[(size_t)(rowb + rr) * N_SZ + col] = f2bf(v);
            }
        }
    }
}

// Fused Vmu + epilogue, 512 blocks x 16 rows.
__global__ __launch_bounds__(256)
void vmu_epilogue_kernel(const ushort_t* __restrict__ mub, const ushort_t* __restrict__ Wvp,
                         const float* __restrict__ f, const float* __restrict__ y,
                         const float* __restrict__ eps, const float* __restrict__ vxp,
                         float* __restrict__ out, float* __restrict__ partials)
{
    __shared__ float vsum[4][16];
    __shared__ float vmu_s[16];
    __shared__ float red[4];
    const int tid = threadIdx.x;
    const int lane = tid & 63;
    const int w = tid >> 6;
    const int q = lane >> 4;
    const int rlo = lane & 15;
    const int r0 = blockIdx.x * 16;

    // ---- stage 1: Vmu via MFMA (16x64 tile per wave) ----
    f32x4 acc[4];
#pragma unroll
    for (int j = 0; j < 4; ++j)
        acc[j] = f32x4{0.f, 0.f, 0.f, 0.f};

    const ushort_t* a0 = mub + (size_t)(r0 + rlo) * N_SZ + q * 8;
    const ushort_t* b0 = Wvp + ((size_t)q * N_SZ + w * 64 + rlo) * 8;
#pragma unroll
    for (int s = 0; s < 8; ++s) {
        bf16x8 af = *(const bf16x8*)(a0 + s * 32);
        bf16x8 bfr[4];
#pragma unroll
        for (int j = 0; j < 4; ++j)
            bfr[j] = *(const bf16x8*)(b0 + s * 4 * N_SZ * 8 + j * 128);
#pragma unroll
        for (int j = 0; j < 4; ++j)
            acc[j] = __builtin_amdgcn_mfma_f32_16x16x32_bf16(af, bfr[j], acc[j], 0, 0, 0);
    }
#pragma unroll
    for (int rr = 0; rr < 4; ++rr) {
        float s = 0.f;
#pragma unroll
        for (int j = 0; j < 4; ++j) { float v = acc[j][rr]; s += v * v; }
#pragma unroll
        for (int m = 1; m < 16; m <<= 1) s += __shfl_xor(s, m, 64);
        if (rlo == 0) vsum[w][q * 4 + rr] = s;
    }
    __syncthreads();
    if (tid < 16)
        vmu_s[tid] = 1e-3f + vsum[0][tid] + vsum[1][tid] + vsum[2][tid] + vsum[3][tid];
    __syncthreads();

    // ---- stage 2: epilogue over 16 rows ----
    float t = 0.f;
    const int n = tid;
#pragma unroll 4
    for (int r = 0; r < 16; ++r) {
        size_t row = (size_t)(r0 + r);
        float mu = f[row * 512 + n];
        float lv = f[row * 512 + 256 + n];
        float var = expf(lv);
        float Vx = vxp[row] + vxp[B_SZ + row] + 1e-3f;
        float Vmu = vmu_s[r];
        float scale = fminf(BETA_F * Vx, Vmu) / Vmu;
        float mus = mu * scale;
        out[row * 256 + n] = mus + sqrtf(var) * eps[row * 256 + n];
        float d = y[row * 256 + n] - mus;
        t += lv + d * d / var;
    }
#pragma unroll
    for (int m = 32; m >= 1; m >>= 1) t += __shfl_down(t, m, 64);
    if (lane == 0) red[w] = t;
    __syncthreads();
    if (tid == 0)
        partials[blockIdx.x] = red[0] + red[1] + red[2] + red[3];
}

// sum 512 partials -> logp_y scalar.
__global__ __launch_bounds__(256)
void reduce_kernel(const float* __restrict__ partials, float* __restrict__ out)
{
    int tid = threadIdx.x;
    float s = partials[tid] + partials[tid + 256];
#pragma unroll
    for (int m = 32; m >= 1; m >>= 1) s += __shfl_down(s, m, 64);
    __shared__ float red[4];
    if ((tid & 63) == 0) red[tid >> 6] = s;
    __syncthreads();
    if (tid == 0)
        out[(size_t)B_SZ * N_SZ] =
            0.5f * (red[0] + red[1] + red[2] + red[3] +
                    (float)N_SZ * LOG2PI_F * (float)B_SZ);
}

// Conversion, fully coalesced: one thread per 8-element k-chunk.
__global__ __launch_bounds__(256)
void convert_kernel(const float* __restrict__ x, const float* __restrict__ W1,
                    const float* __restrict__ W2, const float* __restrict__ Wv,
                    ushort_t* __restrict__ xb, ushort_t* __restrict__ W1p,
                    ushort_t* __restrict__ W2p, ushort_t* __restrict__ Wvp)
{
    const int XC = 262144, W1C = 65536, W2C = 131072;
    int c = blockIdx.x * 256 + threadIdx.x;
    if (c < XC) {
        f32x4 a = *(const f32x4*)(x + (size_t)c * 8);
        f32x4 b = *(const f32x4*)(x + (size_t)c * 8 + 4);
        u16x8 o;
#pragma unroll
        for (int i = 0; i < 4; ++i) { o[i] = f2bf(a[i]); o[4 + i] = f2bf(b[i]); }
        *(u16x8*)(xb + (size_t)c * 8) = o;
    } else if (c < XC + W1C) {
        int d = c - XC;
        int ko = d >> 11, n = d & 2047;
        u16x8 o;
#pragma unroll
        for (int ki = 0; ki < 8; ++ki)
            o[ki] = f2bf(W1[(size_t)(ko * 8 + ki) * H_SZ + n]);
        *(u16x8*)(W1p + (size_t)d * 8) = o;
    } else if (c < XC + W1C + W2C) {
        int d = c - XC - W1C;
        int ko = d >> 9, n = d & 511;
        u16x8 o;
#pragma unroll
        for (int ki = 0; ki < 8; ++ki)
            o[ki] = f2bf(W2[(size_t)(ko * 8 + ki) * 512 + n]);
        *(u16x8*)(W2p + (size_t)d * 8) = o;
    } else {
        int d = c - XC - W1C - W2C;
        int ko = d >> 8, n = d & 255;
        u16x8 o;
#pragma unroll
        for (int ki = 0; ki < 8; ++ki)
            o[ki] = f2bf(Wv[(size_t)(ko * 8 + ki) * N_SZ + n]);
        *(u16x8*)(Wvp + (size_t)d * 8) = o;
    }
}

extern "C" void kernel_launch(void* const* d_in, const int* in_sizes, int n_in,
                              void* d_out, int out_size, void* d_ws, size_t ws_size,
                              hipStream_t stream)
{
    const float* x   = (const float*)d_in[0];
    const float* y   = (const float*)d_in[1];
    const float* eps = (const float*)d_in[2];
    const float* W1  = (const float*)d_in[3];
    const float* b1  = (const float*)d_in[4];
    const float* W2  = (const float*)d_in[5];
    const float* b2  = (const float*)d_in[6];
    const float* Wv  = (const float*)d_in[7];
    float* out = (float*)d_out;

    char* ws = (char*)d_ws;
    size_t off = 0;
    auto alloc = [&](size_t bytes) {
        char* p = ws + off;
        off += (bytes + 255) & ~(size_t)255;
        return p;
    };
    ushort_t* xb  = (ushort_t*)alloc((size_t)B_SZ * N_SZ * 2);
    ushort_t* W1p = (ushort_t*)alloc((size_t)N_SZ * H_SZ * 2);
    ushort_t* W2p = (ushort_t*)alloc((size_t)H_SZ * 512 * 2);
    ushort_t* Wvp = (ushort_t*)alloc((size_t)N_SZ * N_SZ * 2);
    ushort_t* h   = (ushort_t*)alloc((size_t)B_SZ * H_SZ * 2);
    float*    f   = (float*)alloc((size_t)B_SZ * 512 * 4);
    ushort_t* mub = (ushort_t*)alloc((size_t)B_SZ * N_SZ * 2);
    float*    vxp = (float*)alloc((size_t)2 * B_SZ * 4);
    float*    partials = (float*)alloc(512 * 4);

    const int TOTALC = 262144 + 65536 + 131072 + 8192;  // 466944 chunks
    convert_kernel<<<TOTALC / 256, 256, 0, stream>>>(x, W1, W2, Wv, xb, W1p, W2p, Wvp);

    // h = tanh(x@W1 + b1)  (+ fused Vx partials), BK=64 (measured best)
    gemm1_vx_kernel<<<1152, 256, 0, stream>>>(xb, W1p, Wvp, b1, h, vxp);
    // f = h@W2 + b2 ; mub = bf16(mu), BK=128 (measured best)
    gemm2_kernel<<<512, 256, 0, stream>>>(h, W2p, b2, f, mub);
    // Vmu + epilogue fused, 512 blocks
    vmu_epilogue_kernel<<<512, 256, 0, stream>>>(mub, Wvp, f, y, eps, vxp, out, partials);
    reduce_kernel<<<1, 256, 0, stream>>>(partials, out);
}

// Round 13
// 155.362 us; speedup vs baseline: 1.2706x; 1.0317x over previous
//
#include <hip/hip_runtime.h>
#include <stdint.h>

#define B_SZ 8192
#define N_SZ 256
#define H_SZ 2048
#define LOG2PI_F 1.8378770664093453f
#define BETA_F 0.99f

typedef unsigned short ushort_t;
typedef __attribute__((ext_vector_type(8))) __bf16 bf16x8;
typedef __attribute__((ext_vector_type(4))) float f32x4;
typedef __attribute__((ext_vector_type(8))) ushort_t u16x8;

__device__ __forceinline__ ushort_t f2bf(float f) {
    unsigned int u = __float_as_uint(f);
    unsigned int r = (u + 0x7FFFu + ((u >> 16) & 1u)) >> 16;  // RNE
    return (ushort_t)r;
}

__device__ __forceinline__ float fast_tanh(float v) {
    float ex = __expf(2.0f * v);
    return 1.0f - __fdividef(2.0f, ex + 1.0f);
}

__device__ __forceinline__ void async_ld16(const void* g, const char* lds_uniform) {
    __builtin_amdgcn_global_load_lds(
        (const __attribute__((address_space(1))) void*)g,
        (__attribute__((address_space(3))) void*)lds_uniform,
        16, 0, 0);
}

// GEMM1 (tanh -> h_p, k-permuted [H/8][B][8]) fused with Vx. 128x128 tiles,
// BK=64, 1D grid 1152, XCD swizzle. Epilogue: LDS transpose -> 16B coalesced
// stores (was 64x 2B scattered stores -> 1.8x HBM write amplification).
__global__ __launch_bounds__(256, 4)
void gemm1_vx_kernel(const ushort_t* __restrict__ xb, const ushort_t* __restrict__ W1p,
                     const ushort_t* __restrict__ Wvp, const float* __restrict__ b1,
                     ushort_t* __restrict__ hp, float* __restrict__ vxp)
{
    __shared__ __align__(16) char smem[34816];  // loop: sA 16K + sB 16K; epi: st 34K
    char* sA = smem;           // [8 kq][128 m][8] bf16 = 16 KB
    char* sB = smem + 16384;   // [8 kq][128 n][8] bf16 = 16 KB
    const int tid = threadIdx.x;
    const int lane = tid & 63;
    const int w = tid >> 6;
    const int q = lane >> 4;
    const int rlo = lane & 15;
    const int wr = w >> 1, wc = w & 1;

    const int bid = blockIdx.x;
    const int r8 = bid & 7;
    const int u = bid >> 3;       // 0..143
    const int cb = u % 18;
    const int tb = u / 18;        // 0..7
    const int row0 = (r8 + 8 * tb) * 128;

    const bool w1path = cb < 16;
    const int n0 = (w1path ? cb : cb - 16) * 128;
    const ushort_t* Bp = w1path ? W1p : Wvp;
    const int N = w1path ? H_SZ : N_SZ;

    f32x4 acc[4][4];
#pragma unroll
    for (int i = 0; i < 4; ++i)
#pragma unroll
        for (int j = 0; j < 4; ++j)
            acc[i][j] = f32x4{0.f, 0.f, 0.f, 0.f};

    for (int k0 = 0; k0 < N_SZ; k0 += 64) {
        __syncthreads();
#pragma unroll
        for (int r = 0; r < 4; ++r) {
            int c = r * 256 + tid;
            int kq = c >> 7, m = c & 127;
            async_ld16(xb + (size_t)(row0 + m) * N_SZ + k0 + kq * 8, sA + (c << 4));
        }
        int ko0 = k0 >> 3;
#pragma unroll
        for (int r = 0; r < 4; ++r) {
            int c = r * 256 + tid;
            int kq = c >> 7, n = c & 127;
            async_ld16(Bp + ((size_t)(ko0 + kq) * N + n0 + n) * 8, sB + (c << 4));
        }
        __syncthreads();

#pragma unroll
        for (int ks = 0; ks < 2; ++ks) {
            int kq = ks * 4 + q;
            bf16x8 af[4], bfr[4];
#pragma unroll
            for (int i = 0; i < 4; ++i)
                af[i] = *(const bf16x8*)(sA + (((kq << 7) + wr * 64 + i * 16 + rlo) << 4));
#pragma unroll
            for (int j = 0; j < 4; ++j)
                bfr[j] = *(const bf16x8*)(sB + (((kq << 7) + wc * 64 + j * 16 + rlo) << 4));
#pragma unroll
            for (int i = 0; i < 4; ++i)
#pragma unroll
                for (int j = 0; j < 4; ++j)
                    acc[i][j] = __builtin_amdgcn_mfma_f32_16x16x32_bf16(af[i], bfr[j], acc[i][j], 0, 0, 0);
        }
    }

    if (w1path) {
        __syncthreads();  // done with sA/sB reads; reuse LDS as transpose buffer
        ushort_t* st = (ushort_t*)smem;  // [128 rows][stride 136] bf16
#pragma unroll
        for (int j = 0; j < 4; ++j) {
            int coll = wc * 64 + j * 16 + rlo;
            float bv = b1[n0 + coll];
#pragma unroll
            for (int i = 0; i < 4; ++i) {
                int rowl = wr * 64 + i * 16 + q * 4;
#pragma unroll
                for (int rr = 0; rr < 4; ++rr)
                    st[(rowl + rr) * 136 + coll] = f2bf(fast_tanh(acc[i][j][rr] + bv));
            }
        }
        __syncthreads();
        // coalesced store: 2048 chunks x 16B -> hp[(n0/8+ko)*B + row0+m]*8
#pragma unroll
        for (int r = 0; r < 8; ++r) {
            int c = r * 256 + tid;
            int m = c & 127, ko = c >> 7;
            u16x8 v = *(const u16x8*)(st + m * 136 + ko * 8);
            *(u16x8*)(hp + ((size_t)((n0 >> 3) + ko) * B_SZ + row0 + m) * 8) = v;
        }
    } else {
        // Vx partial for col-half (n0>>7): plain store, no atomics
        float* vdst = vxp + (n0 >> 7) * B_SZ;
#pragma unroll
        for (int i = 0; i < 4; ++i) {
#pragma unroll
            for (int rr = 0; rr < 4; ++rr) {
                float s = 0.f;
#pragma unroll
                for (int j = 0; j < 4; ++j) { float v = acc[i][j][rr]; s += v * v; }
#pragma unroll
                for (int m = 1; m < 16; m <<= 1) s += __shfl_xor(s, m, 64);
                if (rlo == 0)
                    vdst[row0 + wr * 64 + i * 16 + q * 4 + rr] = s;
            }
        }
    }
}

// GEMM2: f = h@W2 + b2, mub = bf16(f[:, :256]). A from hp (k-permuted).
// 64x128 tiles, BK=128 (16 iters). grid 512, XCD swizzle.
__global__ __launch_bounds__(256, 2)
void gemm2_kernel(const ushort_t* __restrict__ hp, const ushort_t* __restrict__ W2p,
                  const float* __restrict__ b2, float* __restrict__ f,
                  ushort_t* __restrict__ mub)
{
    __shared__ __align__(16) char smem[49152];
    char* sA = smem;           // [16 kq][64 m][8] bf16 = 16 KB
    char* sB = smem + 16384;   // [16 kq][128 n][8] bf16 = 32 KB
    const int tid = threadIdx.x;
    const int lane = tid & 63;
    const int w = tid >> 6;
    const int q = lane >> 4;
    const int rlo = lane & 15;
    const int wr = w >> 1, wc = w & 1;

    const int bid = blockIdx.x;
    const int r8 = bid & 7;
    const int u = bid >> 3;
    const int cb = u & 3;
    const int tb = u >> 2;
    const int row0 = (r8 + 8 * tb) * 64;
    const int n0 = cb * 128;

    f32x4 acc[2][4];
#pragma unroll
    for (int i = 0; i < 2; ++i)
#pragma unroll
        for (int j = 0; j < 4; ++j)
            acc[i][j] = f32x4{0.f, 0.f, 0.f, 0.f};

    for (int k0 = 0; k0 < H_SZ; k0 += 128) {
        __syncthreads();
        int ko0 = k0 >> 3;
#pragma unroll
        for (int r = 0; r < 4; ++r) {   // A: 1024 chunks from hp, [kq][m][8]
            int c = r * 256 + tid;
            int kq = c >> 6, m = c & 63;
            async_ld16(hp + ((size_t)(ko0 + kq) * B_SZ + row0 + m) * 8, sA + (c << 4));
        }
#pragma unroll
        for (int r = 0; r < 8; ++r) {   // B: 2048 chunks, [kq][n][8]
            int c = r * 256 + tid;
            int kq = c >> 7, n = c & 127;
            async_ld16(W2p + ((size_t)(ko0 + kq) * 512 + n0 + n) * 8, sB + (c << 4));
        }
        __syncthreads();

#pragma unroll
        for (int ks = 0; ks < 4; ++ks) {
            int kq = ks * 4 + q;
            bf16x8 af[2], bfr[4];
#pragma unroll
            for (int i = 0; i < 2; ++i)
                af[i] = *(const bf16x8*)(sA + (((kq << 6) + wr * 32 + i * 16 + rlo) << 4));
#pragma unroll
            for (int j = 0; j < 4; ++j)
                bfr[j] = *(const bf16x8*)(sB + (((kq << 7) + wc * 64 + j * 16 + rlo) << 4));
#pragma unroll
            for (int i = 0; i < 2; ++i)
#pragma unroll
                for (int j = 0; j < 4; ++j)
                    acc[i][j] = __builtin_amdgcn_mfma_f32_16x16x32_bf16(af[i], bfr[j], acc[i][j], 0, 0, 0);
        }
    }

#pragma unroll
    for (int j = 0; j < 4; ++j) {
        int col = n0 + wc * 64 + j * 16 + rlo;
        float bv = b2[col];
#pragma unroll
        for (int i = 0; i < 2; ++i) {
            int rowb = row0 + wr * 32 + i * 16 + q * 4;
#pragma unroll
            for (int rr = 0; rr < 4; ++rr) {
                float v = acc[i][j][rr] + bv;
                f[(size_t)(rowb + rr) * 512 + col] = v;
                if (col < N_SZ)
                    mub[(size_t)(rowb + rr) * N_SZ + col] = f2bf(v);
            }
        }
    }
}

// Fused Vmu + epilogue, 512 blocks x 16 rows.
__global__ __launch_bounds__(256)
void vmu_epilogue_kernel(const ushort_t* __restrict__ mub, const ushort_t* __restrict__ Wvp,
                         const float* __restrict__ f, const float* __restrict__ y,
                         const float* __restrict__ eps, const float* __restrict__ vxp,
                         float* __restrict__ out, float* __restrict__ partials)
{
    __shared__ float vsum[4][16];
    __shared__ float vmu_s[16];
    __shared__ float red[4];
    const int tid = threadIdx.x;
    const int lane = tid & 63;
    const int w = tid >> 6;
    const int q = lane >> 4;
    const int rlo = lane & 15;
    const int r0 = blockIdx.x * 16;

    // ---- stage 1: Vmu via MFMA (16x64 tile per wave) ----
    f32x4 acc[4];
#pragma unroll
    for (int j = 0; j < 4; ++j)
        acc[j] = f32x4{0.f, 0.f, 0.f, 0.f};

    const ushort_t* a0 = mub + (size_t)(r0 + rlo) * N_SZ + q * 8;
    const ushort_t* b0 = Wvp + ((size_t)q * N_SZ + w * 64 + rlo) * 8;
#pragma unroll
    for (int s = 0; s < 8; ++s) {
        bf16x8 af = *(const bf16x8*)(a0 + s * 32);
        bf16x8 bfr[4];
#pragma unroll
        for (int j = 0; j < 4; ++j)
            bfr[j] = *(const bf16x8*)(b0 + s * 4 * N_SZ * 8 + j * 128);
#pragma unroll
        for (int j = 0; j < 4; ++j)
            acc[j] = __builtin_amdgcn_mfma_f32_16x16x32_bf16(af, bfr[j], acc[j], 0, 0, 0);
    }
#pragma unroll
    for (int rr = 0; rr < 4; ++rr) {
        float s = 0.f;
#pragma unroll
        for (int j = 0; j < 4; ++j) { float v = acc[j][rr]; s += v * v; }
#pragma unroll
        for (int m = 1; m < 16; m <<= 1) s += __shfl_xor(s, m, 64);
        if (rlo == 0) vsum[w][q * 4 + rr] = s;
    }
    __syncthreads();
    if (tid < 16)
        vmu_s[tid] = 1e-3f + vsum[0][tid] + vsum[1][tid] + vsum[2][tid] + vsum[3][tid];
    __syncthreads();

    // ---- stage 2: epilogue over 16 rows ----
    float t = 0.f;
    const int n = tid;
#pragma unroll 4
    for (int r = 0; r < 16; ++r) {
        size_t row = (size_t)(r0 + r);
        float mu = f[row * 512 + n];
        float lv = f[row * 512 + 256 + n];
        float var = expf(lv);
        float Vx = vxp[row] + vxp[B_SZ + row] + 1e-3f;
        float Vmu = vmu_s[r];
        float scale = fminf(BETA_F * Vx, Vmu) / Vmu;
        float mus = mu * scale;
        out[row * 256 + n] = mus + sqrtf(var) * eps[row * 256 + n];
        float d = y[row * 256 + n] - mus;
        t += lv + d * d / var;
    }
#pragma unroll
    for (int m = 32; m >= 1; m >>= 1) t += __shfl_down(t, m, 64);
    if (lane == 0) red[w] = t;
    __syncthreads();
    if (tid == 0)
        partials[blockIdx.x] = red[0] + red[1] + red[2] + red[3];
}

// sum 512 partials -> logp_y scalar.
__global__ __launch_bounds__(256)
void reduce_kernel(const float* __restrict__ partials, float* __restrict__ out)
{
    int tid = threadIdx.x;
    float s = partials[tid] + partials[tid + 256];
#pragma unroll
    for (int m = 32; m >= 1; m >>= 1) s += __shfl_down(s, m, 64);
    __shared__ float red[4];
    if ((tid & 63) == 0) red[tid >> 6] = s;
    __syncthreads();
    if (tid == 0)
        out[(size_t)B_SZ * N_SZ] =
            0.5f * (red[0] + red[1] + red[2] + red[3] +
                    (float)N_SZ * LOG2PI_F * (float)B_SZ);
}

// Conversion, fully coalesced: one thread per 8-element k-chunk.
__global__ __launch_bounds__(256)
void convert_kernel(const float* __restrict__ x, const float* __restrict__ W1,
                    const float* __restrict__ W2, const float* __restrict__ Wv,
                    ushort_t* __restrict__ xb, ushort_t* __restrict__ W1p,
                    ushort_t* __restrict__ W2p, ushort_t* __restrict__ Wvp)
{
    const int XC = 262144, W1C = 65536, W2C = 131072;
    int c = blockIdx.x * 256 + threadIdx.x;
    if (c < XC) {
        f32x4 a = *(const f32x4*)(x + (size_t)c * 8);
        f32x4 b = *(const f32x4*)(x + (size_t)c * 8 + 4);
        u16x8 o;
#pragma unroll
        for (int i = 0; i < 4; ++i) { o[i] = f2bf(a[i]); o[4 + i] = f2bf(b[i]); }
        *(u16x8*)(xb + (size_t)c * 8) = o;
    } else if (c < XC + W1C) {
        int d = c - XC;
        int ko = d >> 11, n = d & 2047;
        u16x8 o;
#pragma unroll
        for (int ki = 0; ki < 8; ++ki)
            o[ki] = f2bf(W1[(size_t)(ko * 8 + ki) * H_SZ + n]);
        *(u16x8*)(W1p + (size_t)d * 8) = o;
    } else if (c < XC + W1C + W2C) {
        int d = c - XC - W1C;
        int ko = d >> 9, n = d & 511;
        u16x8 o;
#pragma unroll
        for (int ki = 0; ki < 8; ++ki)
            o[ki] = f2bf(W2[(size_t)(ko * 8 + ki) * 512 + n]);
        *(u16x8*)(W2p + (size_t)d * 8) = o;
    } else {
        int d = c - XC - W1C - W2C;
        int ko = d >> 8, n = d & 255;
        u16x8 o;
#pragma unroll
        for (int ki = 0; ki < 8; ++ki)
            o[ki] = f2bf(Wv[(size_t)(ko * 8 + ki) * N_SZ + n]);
        *(u16x8*)(Wvp + (size_t)d * 8) = o;
    }
}

extern "C" void kernel_launch(void* const* d_in, const int* in_sizes, int n_in,
                              void* d_out, int out_size, void* d_ws, size_t ws_size,
                              hipStream_t stream)
{
    const float* x   = (const float*)d_in[0];
    const float* y   = (const float*)d_in[1];
    const float* eps = (const float*)d_in[2];
    const float* W1  = (const float*)d_in[3];
    const float* b1  = (const float*)d_in[4];
    const float* W2  = (const float*)d_in[5];
    const float* b2  = (const float*)d_in[6];
    const float* Wv  = (const float*)d_in[7];
    float* out = (float*)d_out;

    char* ws = (char*)d_ws;
    size_t off = 0;
    auto alloc = [&](size_t bytes) {
        char* p = ws + off;
        off += (bytes + 255) & ~(size_t)255;
        return p;
    };
    ushort_t* xb  = (ushort_t*)alloc((size_t)B_SZ * N_SZ * 2);
    ushort_t* W1p = (ushort_t*)alloc((size_t)N_SZ * H_SZ * 2);
    ushort_t* W2p = (ushort_t*)alloc((size_t)H_SZ * 512 * 2);
    ushort_t* Wvp = (ushort_t*)alloc((size_t)N_SZ * N_SZ * 2);
    ushort_t* hp  = (ushort_t*)alloc((size_t)B_SZ * H_SZ * 2);
    float*    f   = (float*)alloc((size_t)B_SZ * 512 * 4);
    ushort_t* mub = (ushort_t*)alloc((size_t)B_SZ * N_SZ * 2);
    float*    vxp = (float*)alloc((size_t)2 * B_SZ * 4);
    float*    partials = (float*)alloc(512 * 4);

    const int TOTALC = 262144 + 65536 + 131072 + 8192;  // 466944 chunks
    convert_kernel<<<TOTALC / 256, 256, 0, stream>>>(x, W1, W2, Wv, xb, W1p, W2p, Wvp);

    // h_p = tanh(x@W1 + b1) k-permuted (+ fused Vx partials), BK=64
    gemm1_vx_kernel<<<1152, 256, 0, stream>>>(xb, W1p, Wvp, b1, hp, vxp);
    // f = h@W2 + b2 ; mub = bf16(mu), BK=128, A from hp
    gemm2_kernel<<<512, 256, 0, stream>>>(hp, W2p, b2, f, mub);
    // Vmu + epilogue fused, 512 blocks
    vmu_epilogue_kernel<<<512, 256, 0, stream>>>(mub, Wvp, f, y, eps, vxp, out, partials);
    reduce_kernel<<<1, 256, 0, stream>>>(partials, out);
}